// Round 10
// baseline (2989.961 us; speedup 1.0000x reference)
//
#include <hip/hip_runtime.h>
#include <stdint.h>
#include <math.h>

#define NB  512
#define TT  128
#define DXX 256
#define DUU 32
#define DZZ 128
#define DWW 64
#define MMM 16
#define HHH 128
#define G4  512   // 4*H

typedef __attribute__((ext_vector_type(8))) short bf16x8;
typedef __attribute__((ext_vector_type(4))) float f32x4;
#define MFMA(a,b,c) __builtin_amdgcn_mfma_f32_16x16x32_bf16(a,b,c,0,0,0)
#define MF8(a,b,c)  __builtin_amdgcn_mfma_f32_16x16x32_fp8_fp8(a,b,c,0,0,0)

__device__ __forceinline__ float sigf(float x){ return 1.f/(1.f+__expf(-x)); }
__device__ __forceinline__ float fast_tanh(float x){
    float e = __expf(2.f*x);
    return 1.f - 2.f/(e + 1.f);
}
__device__ __forceinline__ unsigned int f2bf(float f){
    uint32_t u = __float_as_uint(f);
    uint32_t r = (u + 0x7fffu + ((u >> 16) & 1u)) >> 16;
    return r;
}
__device__ __forceinline__ float bf2f(unsigned short u){
    return __uint_as_float(((uint32_t)u) << 16);
}
// OCP e4m3fn encode, RNE, subnormal-correct, clamp to +-448
__device__ __forceinline__ unsigned int f2e4m3(float f){
    uint32_t u = __float_as_uint(f);
    uint32_t s = (u >> 24) & 0x80u;
    uint32_t a = u & 0x7fffffffu;
    if (a >= 0x43e00000u) return s | 0x7eu;
    int exp = (int)(a >> 23) - 127;
    uint32_t mant = a & 0x7fffffu;
    uint32_t code;
    if (exp >= -6){
        uint32_t keep = ((uint32_t)(exp + 7) << 3) | (mant >> 20);
        uint32_t rem = mant & 0xfffffu;
        if (rem > 0x80000u || (rem == 0x80000u && (keep & 1))) keep++;
        code = keep;
        if (code >= 0x7fu) code = 0x7eu;
    } else {
        int rs = 14 - exp;           // 23 - (exp + 9)
        if (rs >= 33) return s;
        uint64_t full = (uint64_t)(mant | 0x800000u);
        uint64_t q = full >> rs;
        uint64_t rem = full & (((uint64_t)1 << rs) - 1);
        uint64_t half = (uint64_t)1 << (rs - 1);
        if (rem > half || (rem == half && (q & 1))) q++;
        code = (uint32_t)q;
    }
    return s | code;
}

__device__ __forceinline__ void stage1k(const void* gsrc, void* ldst, int ln)
{
    __builtin_amdgcn_global_load_lds(
        (const __attribute__((address_space(1))) void*)((const char*)gsrc + ln*16),
        (__attribute__((address_space(3))) void*)ldst, 16, 0, 0);
}
__device__ __forceinline__ void stage32k(const void* gsrc, void* ldst, int tid)
{
    const char* g = (const char*)gsrc;
    char* l = (char*)ldst;
    const int lane = tid & 63;
    const int wv   = tid >> 6;
    #pragma unroll
    for (int it = 0; it < 8; it++){
        const int off = it*4096 + wv*1024;
        __builtin_amdgcn_global_load_lds(
            (const __attribute__((address_space(1))) void*)(g + off + lane*16),
            (__attribute__((address_space(3))) void*)(l + off),
            16, 0, 0);
    }
}

// ===========================================================================
// k_prep2: bf16 A-frag tiles for G1..G4, REPLICATED 8x (copy-major).
// blockIdx = copy*180 + T; dst tile index = blockIdx.
// ===========================================================================
__global__ __launch_bounds__(256) void k_prep2(
    const float* __restrict__ wp_w1, const float* __restrict__ wp_w2,
    const float* __restrict__ vp_w1, const float* __restrict__ vp_w2,
    unsigned short* __restrict__ frag)
{
    const int T = blockIdx.x % 180;
    unsigned short* dst = frag + (size_t)blockIdx.x*512;
    for (int e = threadIdx.x; e < 512; e += 256){
        const int lane = e >> 3, j = e & 7;
        const int m16 = lane & 15, kq = lane >> 4;
        const int kk = 8*kq + j;
        float v = 0.f;
        if (T < 104){
            const int ct = T/13, kt = T%13;
            v = wp_w1[(size_t)(16*ct + m16)*416 + 32*kt + kk];
        } else if (T < 136){
            const int i = T-104, ct = i/4, kt = i%4;
            v = wp_w2[(size_t)(16*ct + m16)*128 + 32*kt + kk];
        } else if (T < 176){
            const int i = T-136, ct = i/5, kt = i%5;
            v = vp_w1[(size_t)(16*ct + m16)*160 + 32*kt + kk];
        } else {
            const int kt = T-176;
            v = vp_w2[(size_t)m16*128 + 32*kt + kk];
        }
        dst[e] = (unsigned short)f2bf(v);
    }
}

// ===========================================================================
// k_prep8: fp8 A-frags for ABC (x16 scale), REPLICATED 8x (copy-major).
// blockIdx = copy*64 + lin; lin = (wv, pair). 7168B = 14 frags x 512B.
// ===========================================================================
__global__ __launch_bounds__(256) void k_prep8(
    const float* __restrict__ Amat, const float* __restrict__ Bmat,
    const float* __restrict__ Cmat, unsigned char* __restrict__ frag8)
{
    const int lin = blockIdx.x & 63;
    const int wv = lin >> 3, pair = lin & 7;
    unsigned char* dst = frag8 + (size_t)blockIdx.x*7168;
    for (int d = threadIdx.x*4; d < 7168; d += 1024){
        uint32_t pk = 0;
        #pragma unroll
        for (int i = 0; i < 4; i++){
            const int B = d + i;
            const int f = B >> 9, r = B & 511;
            const int lane = r >> 3, jj = r & 7;
            const int m = 2*pair + (f >= 7 ? 1 : 0);
            const int kt = (f >= 7) ? f-7 : f;
            const int col = wv*16 + (lane & 15);
            const int k = kt*32 + (lane >> 4)*8 + jj;
            float v;
            if (k < 128)      v = Amat[((size_t)m*128 + col)*128 + k];
            else if (k < 160) v = Bmat[((size_t)m*128 + col)*32 + (k-128)];
            else              v = Cmat[((size_t)m*128 + col)*64 + (k-160)];
            pk |= f2e4m3(v * 16.f) << (8*i);
        }
        *(uint32_t*)(dst + d) = pk;
    }
}

// ---------------------------------------------------------------------------
// k_prep_xg / k_prep_lo (unchanged)
// ---------------------------------------------------------------------------
__global__ __launch_bounds__(256) void k_prep_xg(const float* __restrict__ Wih,
                                                 unsigned short* __restrict__ fragx)
{
    const int T = blockIdx.x;
    const int ct = T >> 3, kt = T & 7;
    unsigned short* dst = fragx + (size_t)T*512;
    for (int e = threadIdx.x; e < 512; e += 256){
        const int lane = e >> 3, j = e & 7;
        const int m16 = lane & 15, kq = lane >> 4;
        const int kk = 8*kq + j;
        float v = Wih[(size_t)(16*ct + m16)*DXX + 32*kt + kk];
        dst[e] = (unsigned short)f2bf(v);
    }
}

__global__ __launch_bounds__(256) void k_prep_lo(
    const float* __restrict__ Whh,
    const float* __restrict__ ob_w1, const float* __restrict__ ob_w2,
    unsigned short* __restrict__ blstm, unsigned short* __restrict__ bob)
{
    const int tile = blockIdx.x;
    unsigned short* dst; int lt;
    if (tile < 4){ dst = blstm + (size_t)tile*16384; lt = 1; }
    else { dst = bob + (size_t)(tile-4)*16384; lt = 2; }
    for (int e = threadIdx.x; e < 16384; e += 256){
        const int g = e >> 7, p = e & 127;
        const int s = p >> 3, j = p & 7;
        const int k = ((s ^ (g & 7)) << 3) | j;
        float v;
        if (lt == 1) v = Whh[(size_t)(tile*128 + g)*128 + k];
        else {
            const int tt = tile - 4;
            if (tt == 0) v = ob_w1[g*128 + k];
            else         v = ob_w2[(size_t)((tt-1)*128 + g)*128 + k];
        }
        dst[e] = (unsigned short)f2bf(v);
    }
}

// ===========================================================================
// k_prep_in: input images + fp8 u image (IUf)  (unchanged from R8)
// ===========================================================================
__global__ __launch_bounds__(256) void k_prep_in(
    const float* __restrict__ X, const float* __restrict__ U, const float* __restrict__ EPS,
    unsigned short* __restrict__ IX, unsigned short* __restrict__ IU,
    unsigned short* __restrict__ IE, unsigned char* __restrict__ IUf)
{
    const int b  = blockIdx.x;
    const int tt = blockIdx.y;
    const int n0 = b*16;
    unsigned short* dx = IX + ((size_t)b*127 + tt)*4096;
    for (int h = threadIdx.x; h < 4096; h += 256){
        const int o = h >> 9, l = (h >> 3) & 63, j = h & 7;
        const int r = 2*o + (l >> 5), v = l & 31;
        const int s = v ^ (r & 7);
        dx[h] = (unsigned short)f2bf(X[((size_t)(n0+r)*TT + tt+1)*DXX + s*8 + j]);
    }
    unsigned short* du = IU + ((size_t)b*127 + tt)*512;
    for (int h = threadIdx.x; h < 512; h += 256){
        const int l = h >> 3, j = h & 7;
        const int r = l >> 2, v = l & 3;
        const int qq = v ^ (r & 3);
        du[h] = (unsigned short)f2bf(U[((size_t)(n0+r)*TT + tt)*DUU + qq*8 + j]);
    }
    unsigned short* de = IE + ((size_t)b*127 + tt)*1024;
    for (int h = threadIdx.x; h < 1024; h += 256){
        const int e2 = h >> 9, l = (h >> 3) & 63, j = h & 7;
        const int r = 8*e2 + (l >> 3);
        de[h] = (unsigned short)f2bf(EPS[((size_t)(n0+r)*TT + tt+1)*DWW + (l&7)*8 + j]);
    }
    unsigned char* df = IUf + ((size_t)b*127 + tt)*512;
    for (int h = threadIdx.x; h < 512; h += 256){
        const int smp = h >> 5, sp = (h >> 3) & 3, j = h & 7;
        const int ud = ((sp ^ (smp & 3))*8) + j;
        df[h] = (unsigned char)f2e4m3(U[((size_t)(n0+smp)*TT + tt)*DUU + ud]);
    }
}

// ---------------------------------------------------------------------------
// fp32 dense helper (k_init only)
// ---------------------------------------------------------------------------
template<int ACT>
__device__ void dense(const float* __restrict__ W, const float* __restrict__ bias,
                      int C, int K, const float* sIn, int ldi,
                      float* sOut, int ldo, float* sWt)
{
    const int tid = threadIdx.x;
    const int g   = tid & 127;
    const int rq  = tid >> 7;
    const int r0  = 2*rq, r1 = 2*rq+1;
    for (int cb = 0; cb < C; cb += 128){
        float acc0 = 0.f, acc1 = 0.f;
        for (int kb = 0; kb < K; kb += 64){
            const int kw = (K - kb < 64) ? (K - kb) : 64;
            __syncthreads();
            if (kw == 64){
                for (int l = tid; l < 128*64; l += 256){
                    int gg = l >> 6, kk = l & 63;
                    int cx = cb + gg;
                    sWt[gg*65 + kk] = (cx < C) ? W[(size_t)cx*K + kb + kk] : 0.f;
                }
            } else {
                for (int l = tid; l < 128*32; l += 256){
                    int gg = l >> 5, kk = l & 31;
                    int cx = cb + gg;
                    sWt[gg*65 + kk] = (cx < C) ? W[(size_t)cx*K + kb + kk] : 0.f;
                }
            }
            __syncthreads();
            const float* ip0 = sIn + r0*ldi + kb;
            const float* ip1 = sIn + r1*ldi + kb;
            const float* wp  = sWt + g*65;
            #pragma unroll 8
            for (int k = 0; k < kw; k++){
                float wv = wp[k];
                acc0 += ip0[k]*wv;
                acc1 += ip1[k]*wv;
            }
        }
        int cx = cb + g;
        if (cx < C){
            float b = bias ? bias[cx] : 0.f;
            float v0 = acc0 + b, v1 = acc1 + b;
            if (ACT == 1){ v0 = fmaxf(v0, 0.f); v1 = fmaxf(v1, 0.f); }
            else if (ACT == 2){ v0 = fast_tanh(v0); v1 = fast_tanh(v1); }
            sOut[r0*ldo + cx] = v0;
            sOut[r1*ldo + cx] = v1;
        }
    }
}

// ---------------------------------------------------------------------------
// K1: xg GEMM (unchanged)
// ---------------------------------------------------------------------------
__global__ __launch_bounds__(512) void k_xg2(const float* __restrict__ X,
                                             const unsigned short* __restrict__ fragx,
                                             const float* __restrict__ bias,
                                             unsigned short* __restrict__ xgb)
{
    __shared__ __align__(16) short sXl[16*256];
    const int tid = threadIdx.x;
    const size_t row0 = (size_t)blockIdx.x * 16;
    const int wv = tid >> 6, ln = tid & 63;
    const int rr = ln & 15, q = ln >> 4;
    const int sx7 = rr & 7;
    {
        const int r = tid >> 5, sl = tid & 31;
        const float* xp = &X[(row0 + r)*DXX + sl*8];
        float4 a0 = *(const float4*)xp;
        float4 a1 = *(const float4*)(xp+4);
        int4 pk;
        pk.x = f2bf(a0.x) | (f2bf(a0.y)<<16);
        pk.y = f2bf(a0.z) | (f2bf(a0.w)<<16);
        pk.z = f2bf(a1.x) | (f2bf(a1.y)<<16);
        pk.w = f2bf(a1.z) | (f2bf(a1.w)<<16);
        *(int4*)&sXl[r*256 + ((sl ^ (r&7))<<3)] = pk;
    }
    __syncthreads();
    #pragma unroll
    for (int ci = 0; ci < 4; ci++){
        const int ct = wv*4 + ci;
        const short* pA = (const short*)fragx + (size_t)(ct*8)*512 + ln*8;
        bf16x8 af[8];
        #pragma unroll
        for (int kt = 0; kt < 8; kt++) af[kt] = *(const bf16x8*)(pA + kt*512);
        f32x4 d = {0.f,0.f,0.f,0.f};
        #pragma unroll
        for (int kt = 0; kt < 8; kt++){
            bf16x8 b = *(const bf16x8*)&sXl[rr*256 + (((4*kt+q) ^ sx7)<<3)];
            d = MFMA(af[kt], b, d);
        }
        const f32x4 bb = *(const f32x4*)&bias[ct*16 + q*4];
        uint2 pk;
        pk.x = f2bf(d[0]+bb[0]) | (f2bf(d[1]+bb[1])<<16);
        pk.y = f2bf(d[2]+bb[2]) | (f2bf(d[3]+bb[3])<<16);
        *(uint2*)&xgb[(row0 + rr)*G4 + ct*16 + q*4] = pk;
    }
}

// ---------------------------------------------------------------------------
// K2: forward LSTM (unchanged)
// ---------------------------------------------------------------------------
__global__ __launch_bounds__(256) void k_lstm(const unsigned short* __restrict__ xgb,
                                              const unsigned short* __restrict__ blob,
                                              float* __restrict__ h0)
{
    __shared__ __align__(16) char sWh[4][32768];
    __shared__ __align__(16) float sHh[2][128];
    const int tid = threadIdx.x;
    const int n0 = blockIdx.x * 2;
    const int g = tid & 127, rh = tid >> 7;
    #pragma unroll
    for (int i = 0; i < 4; i++)
        stage32k((const char*)blob + (size_t)i*32768, sWh[i], tid);
    sHh[tid >> 7][tid & 127] = 0.f;
    float cc = 0.f;
    asm volatile("s_waitcnt vmcnt(0)" ::: "memory");
    __syncthreads();
    const size_t xbase = ((size_t)(n0+rh)*TT)*G4 + g;
    for (int t = 0; t < TT; t++){
        float xv[4];
        #pragma unroll
        for (int ct = 0; ct < 4; ct++) xv[ct] = bf2f(xgb[xbase + (size_t)t*G4 + ct*128]);
        float a[4] = {0.f,0.f,0.f,0.f};
        #pragma unroll
        for (int s = 0; s < 16; s++){
            const float* ip = &sHh[rh][s*8];
            float4 u0 = *(const float4*)ip;
            float4 u1 = *(const float4*)(ip+4);
            float in[8] = {u0.x,u0.y,u0.z,u0.w,u1.x,u1.y,u1.z,u1.w};
            #pragma unroll
            for (int ct = 0; ct < 4; ct++){
                const uint32_t* wp = (const uint32_t*)(sWh[ct] + g*256 + ((s ^ (g & 7)) << 4));
                #pragma unroll
                for (int d = 0; d < 4; d++){
                    uint32_t w2 = wp[d];
                    a[ct] = fmaf(__uint_as_float(w2 << 16),        in[2*d],   a[ct]);
                    a[ct] = fmaf(__uint_as_float(w2 & 0xffff0000u), in[2*d+1], a[ct]);
                }
            }
        }
        __syncthreads();
        float ii = sigf(a[0] + xv[0]);
        float ff = sigf(a[1] + xv[1]);
        float gg = fast_tanh(a[2] + xv[2]);
        float oo = sigf(a[3] + xv[3]);
        cc = ff*cc + ii*gg;
        float hh = oo*fast_tanh(cc);
        sHh[rh][g] = hh;
        __syncthreads();
    }
    h0[(size_t)(n0+rh)*HHH + g] = sHh[rh][g];
}

// ---------------------------------------------------------------------------
// K3: init net (unchanged)
// ---------------------------------------------------------------------------
__global__ __launch_bounds__(256) void k_init(
    const float* __restrict__ X,
    const float* __restrict__ bw_Wih, const float* __restrict__ bw_b,
    const float* __restrict__ i1w, const float* __restrict__ i1b,
    const float* __restrict__ i2w, const float* __restrict__ i2b,
    const float* __restrict__ z1w, const float* __restrict__ z1b,
    const float* __restrict__ z2w, const float* __restrict__ z2b,
    const float* __restrict__ eps1, const float* __restrict__ h0,
    float* __restrict__ zb, float* __restrict__ wm, float* __restrict__ wsd)
{
    __shared__ float sX[4*260];
    __shared__ float sG[4*516];
    __shared__ float sH0[4*260];
    __shared__ float sT[4*132];
    __shared__ float sP[4*132];
    __shared__ float sWt[128*65];
    const int tid = threadIdx.x;
    const int n0  = blockIdx.x * 4;
    for (int l = tid; l < 4*256; l += 256){
        int r = l >> 8, k = l & 255;
        sX[r*260+k] = X[((size_t)(n0+r)*TT + (TT-1))*DXX + k];
    }
    for (int l = tid; l < 4*128; l += 256){
        int r = l >> 7, j = l & 127;
        sH0[r*260+j] = h0[(size_t)(n0+r)*HHH + j];
    }
    dense<0>(bw_Wih, bw_b, 512, 256, sX, 260, sG, 516, sWt);
    __syncthreads();
    for (int l = tid; l < 4*128; l += 256){
        int r = l >> 7, j = l & 127;
        float gi = sG[r*516 + j];
        float gv = sG[r*516 + 256 + j];
        float go = sG[r*516 + 384 + j];
        float c  = sigf(gi)*fast_tanh(gv);
        sH0[r*260 + 128 + j] = sigf(go)*fast_tanh(c);
    }
    dense<1>(i1w, i1b, 128, 256, sH0, 260, sT, 132, sWt);
    dense<0>(i2w, i2b, 128, 128, sT, 132, sP, 132, sWt);
    __syncthreads();
    for (int l = tid; l < 4*64; l += 256){
        int r = l >> 6, j = l & 63;
        float m0 = sP[r*132 + j];
        float s0 = __expf(sP[r*132 + 64 + j]) + 1e-5f;
        float w1 = m0 + s0*eps1[(size_t)(n0+r)*DWW + j];
        wm[((size_t)(n0+r)*TT)*DWW + j]  = m0;
        wsd[((size_t)(n0+r)*TT)*DWW + j] = s0;
        sX[r*68 + j] = w1;
    }
    dense<1>(z1w, z1b, 128, 64, sX, 68, sT, 132, sWt);
    dense<0>(z2w, z2b, 128, 128, sT, 132, sP, 132, sWt);
    __syncthreads();
    for (int l = tid; l < 4*128; l += 256){
        int r = l >> 7, j = l & 127;
        zb[((size_t)(n0+r)*TT)*DZZ + j] = sP[r*132+j];
    }
}

// ===========================================================================
// K4: MFMA scan, fp8 ABC stream (weights x16, alpha/16). 12 chunks/step.
// R10 delta vs R8: blobs replicated 8x; block reads copy blockIdx&7.
// ===========================================================================
__device__ __forceinline__ int blobIdx(int i, int wv){
    if (i < 13)  return wv*13 + i;
    if (i < 18)  return 136 + wv*5 + (i-13);
    if (i < 22)  return 104 + wv*4 + (i-18);
    if (i < 26)  return 176 + (i-22);
    return 0;
}

#define VWAIT() do{ asm volatile("s_waitcnt vmcnt(7)" ::: "memory"); \
                    __builtin_amdgcn_sched_barrier(0); }while(0)
#define LWAIT() do{ asm volatile("s_waitcnt lgkmcnt(0)" ::: "memory"); \
                    __builtin_amdgcn_sched_barrier(0); }while(0)
#define BAR()   __builtin_amdgcn_s_barrier()

__global__ __launch_bounds__(512) void k_scan(
    const float* __restrict__ wp_b1, const float* __restrict__ wp_b2,
    const float* __restrict__ vp_b1, const float* __restrict__ vp_b2,
    const short* __restrict__ frag, const unsigned char* __restrict__ frag8,
    const unsigned short* __restrict__ IX, const unsigned short* __restrict__ IU,
    const unsigned short* __restrict__ IE, const unsigned char* __restrict__ IUf,
    float* __restrict__ zb, float* __restrict__ wm, float* __restrict__ wsd)
{
    __shared__ __align__(16) short sRing[57344];   // 8 waves x 2 bufs x 7KB
    __shared__ __align__(16) short sXr[4096];
    __shared__ __align__(16) short sZr[2048];      // bf16 z
    __shared__ __align__(16) short sUr[2][512];    // bf16 u
    __shared__ __align__(16) short sEr[1024];
    __shared__ __align__(16) short sH1[2048];
    __shared__ __align__(16) short sH2[2048];
    __shared__ __align__(16) char  sZf[2048];      // fp8 z: 16 x 128B
    __shared__ __align__(16) char  sUf[2][512];    // fp8 u: 16 x 32B
    __shared__ __align__(16) char  sWf[1024];      // fp8 w: 16 x 64B
    __shared__ __align__(16) float sPW[16*132];
    __shared__ __align__(16) float sL [16*20];
    __shared__ float sAl[16*17];

    const int tid = threadIdx.x;
    const int n0  = blockIdx.x * 16;
    const int wv  = tid >> 6;
    const int ln  = tid & 63;
    const int smp = ln & 15, q = ln >> 4;
    const int sx7 = smp & 7;
    char* ringB = (char*)sRing + wv*14336;
    const int cp180 = (blockIdx.x & 7)*180;        // bf16 blob copy offset (tiles)
    const int cp64  = (blockIdx.x & 7)*64;         // fp8 blob copy offset (blocks)

    const f32x4 bw1 = *(const f32x4*)&wp_b1[wv*16 + q*4];
    const f32x4 bw2 = *(const f32x4*)&wp_b2[wv*16 + q*4];
    const f32x4 bv1 = *(const f32x4*)&vp_b1[wv*16 + q*4];
    f32x4 bv2 = {0.f,0.f,0.f,0.f};
    if (wv == 0) bv2 = *(const f32x4*)&vp_b2[q*4];

    #define ISSUE_CHUNK(cc_) do{ const int c2_ = (cc_) % 12; \
        if (c2_ < 4){ _Pragma("unroll") \
            for (int k7 = 0; k7 < 7; k7++) \
                stage1k((const char*)frag + ((size_t)cp180 + blobIdx(c2_*7 + k7, wv))*1024, \
                        ringB + (c2_&1)*7168 + k7*1024, ln); \
        } else { _Pragma("unroll") \
            for (int k7 = 0; k7 < 7; k7++) \
                stage1k((const char*)frag8 + (size_t)(cp64 + wv*8 + (c2_-4))*7168 + k7*1024, \
                        ringB + (c2_&1)*7168 + k7*1024, ln); } }while(0)
    #define AFRAG(gi_)  (*(const bf16x8*)(ringB + (((gi_)/7)&1)*7168 + ((gi_)%7)*1024 + ln*16))
    #define AF8(bf_,f_) (*(const long*)(ringB + (bf_)*7168 + (f_)*512 + ln*8))
    #define BX(kt_)  (*(const bf16x8*)&sXr[smp*256 + (((4*(kt_)+q) ^ sx7)<<3)])
    #define BZ(kz_)  (*(const bf16x8*)&sZr[smp*128 + (((4*(kz_)+q) ^ sx7)<<3)])
    #define BH1(kt_) (*(const bf16x8*)&sH1[smp*128 + (((4*(kt_)+q) ^ sx7)<<3)])
    #define BH2(kt_) (*(const bf16x8*)&sH2[smp*128 + (((4*(kt_)+q) ^ sx7)<<3)])

    auto issue_inputs = [&](int tt){
        const size_t ib = (size_t)blockIdx.x*127 + tt;
        const char* bx8 = (const char*)IX + ib*8192;
        stage1k(bx8 + wv*1024, (char*)sXr + wv*1024, ln);
        if (wv == 0)      stage1k((const char*)IU + ib*1024, (char*)sUr[tt&1], ln);
        else if (wv == 1) stage1k((const char*)IE + ib*2048,        (char*)sEr,        ln);
        else if (wv == 2) stage1k((const char*)IE + ib*2048 + 1024, (char*)sEr + 1024, ln);
        else if (wv == 3){ if (ln < 32) stage1k((const char*)IUf + ib*512, sUf[tt&1], ln); }
    };

    // ---- prologue ----
    issue_inputs(0);
    if (tid < 256){
        const int zs = tid >> 4, sl = tid & 15;
        const float* zp = &zb[((size_t)(n0+zs)*TT)*DZZ + sl*8];
        float4 a0 = *(const float4*)zp;
        float4 a1 = *(const float4*)(zp+4);
        int4 pk;
        pk.x = f2bf(a0.x) | (f2bf(a0.y)<<16);
        pk.y = f2bf(a0.z) | (f2bf(a0.w)<<16);
        pk.z = f2bf(a1.x) | (f2bf(a1.y)<<16);
        pk.w = f2bf(a1.z) | (f2bf(a1.w)<<16);
        *(int4*)&sZr[zs*128 + ((sl ^ (zs&7))<<3)] = pk;
        uint2 p8;
        p8.x = f2e4m3(a0.x) | (f2e4m3(a0.y)<<8) | (f2e4m3(a0.z)<<16) | (f2e4m3(a0.w)<<24);
        p8.y = f2e4m3(a1.x) | (f2e4m3(a1.y)<<8) | (f2e4m3(a1.z)<<16) | (f2e4m3(a1.w)<<24);
        *(uint2*)&sZf[zs*128 + ((sl ^ (zs&7))<<3)] = p8;
    }
    ISSUE_CHUNK(0);
    ISSUE_CHUNK(1);
    asm volatile("s_waitcnt vmcnt(0)" ::: "memory");
    __builtin_amdgcn_sched_barrier(0);
    LWAIT(); BAR();

    for (int t = 0; t < TT-1; t++){
        const short* sUc = sUr[t&1];
        bf16x8 bu = *(const bf16x8*)&sUc[smp*32 + ((q ^ (sx7&3))<<3)];

        // ============ phase A
        VWAIT();                                   // c0 landed
        f32x4 d1a = {0.f,0.f,0.f,0.f}, d1b = {0.f,0.f,0.f,0.f};
        d1a = MFMA(AFRAG(0), BX(0), d1a); d1b = MFMA(AFRAG(1), BX(1), d1b);
        d1a = MFMA(AFRAG(2), BX(2), d1a); d1b = MFMA(AFRAG(3), BX(3), d1b);
        d1a = MFMA(AFRAG(4), BX(4), d1a); d1b = MFMA(AFRAG(5), BX(5), d1b);
        d1a = MFMA(AFRAG(6), BX(6), d1a);
        ISSUE_CHUNK(2);
        VWAIT();                                   // c1 landed
        d1b = MFMA(AFRAG(7), BX(7), d1b);
        d1a = MFMA(AFRAG(8), BZ(0), d1a); d1b = MFMA(AFRAG(9), BZ(1), d1b);
        d1a = MFMA(AFRAG(10), BZ(2), d1a); d1b = MFMA(AFRAG(11), BZ(3), d1b);
        d1a = MFMA(AFRAG(12), bu, d1a);
        f32x4 d3a = {0.f,0.f,0.f,0.f}, d3b = {0.f,0.f,0.f,0.f};
        d3a = MFMA(AFRAG(13), BZ(0), d3a);
        ISSUE_CHUNK(3);
        VWAIT();                                   // c2 landed
        d3b = MFMA(AFRAG(14), BZ(1), d3b); d3a = MFMA(AFRAG(15), BZ(2), d3a);
        d3b = MFMA(AFRAG(16), BZ(3), d3b); d3a = MFMA(AFRAG(17), bu, d3a);
        bf16x8 aG2a = AFRAG(18), aG2b = AFRAG(19), aG2c = AFRAG(20); // pre-read (b0)
        {
            f32x4 d1 = d1a + d1b, d3 = d3a + d3b;
            float v0 = fast_tanh(d1[0]+bw1[0]);
            float v1 = fast_tanh(d1[1]+bw1[1]);
            float v2 = fast_tanh(d1[2]+bw1[2]);
            float v3 = fast_tanh(d1[3]+bw1[3]);
            const int slot = 2*wv + (q>>1);
            const int baseh = smp*128 + ((slot ^ sx7)<<3) + (q&1)*4;
            *(unsigned int*)&sH1[baseh]   = f2bf(v0) | (f2bf(v1)<<16);
            *(unsigned int*)&sH1[baseh+2] = f2bf(v2) | (f2bf(v3)<<16);
            float w0 = fmaxf(d3[0]+bv1[0], 0.f);
            float w1 = fmaxf(d3[1]+bv1[1], 0.f);
            float w2 = fmaxf(d3[2]+bv1[2], 0.f);
            float w3 = fmaxf(d3[3]+bv1[3], 0.f);
            *(unsigned int*)&sH2[baseh]   = f2bf(w0) | (f2bf(w1)<<16);
            *(unsigned int*)&sH2[baseh+2] = f2bf(w2) | (f2bf(w3)<<16);
        }
        ISSUE_CHUNK(4);                            // b0 consumed (incl pre-reads)
        LWAIT(); BAR();

        // ============ phase B
        VWAIT();                                   // c3 landed
        {
            f32x4 d2a = {0.f,0.f,0.f,0.f}, d2b = {0.f,0.f,0.f,0.f};
            d2a = MFMA(aG2a, BH1(0), d2a); d2b = MFMA(aG2b, BH1(1), d2b);
            d2a = MFMA(aG2c, BH1(2), d2a); d2b = MFMA(AFRAG(21), BH1(3), d2b);
            f32x4 o = d2a + d2b + bw2;
            *(f32x4*)&sPW[smp*132 + wv*16 + q*4] = o;
            if (wv == 0){
                f32x4 d4a = {0.f,0.f,0.f,0.f}, d4b = {0.f,0.f,0.f,0.f};
                d4a = MFMA(AFRAG(22), BH2(0), d4a); d4b = MFMA(AFRAG(23), BH2(1), d4b);
                d4a = MFMA(AFRAG(24), BH2(2), d4a); d4b = MFMA(AFRAG(25), BH2(3), d4b);
                f32x4 o4 = d4a + d4b + bv2;
                *(f32x4*)&sL[smp*20 + q*4] = o4;
            }
        }
        ISSUE_CHUNK(5);                            // b1 consumed
        LWAIT(); BAR();

        // ============ phase C: w-update + softmax (alpha/16) + input prefetch
        {
            const int cs = wv, cj = ln;
            float e0 = bf2f((unsigned short)sEr[cs*64 + cj]);
            float e1 = bf2f((unsigned short)sEr[(cs+8)*64 + cj]);
            float m0 = sPW[cs*132 + cj];
            float s0 = __expf(sPW[cs*132 + 64 + cj]) + 0.01f;
            float m1 = sPW[(cs+8)*132 + cj];
            float s1 = __expf(sPW[(cs+8)*132 + 64 + cj]) + 0.01f;
            float w0 = m0 + s0*e0;
            float w1 = m1 + s1*e1;
            wm [((size_t)(n0+cs  )*TT + t+1)*DWW + cj] = m0;
            wsd[((size_t)(n0+cs  )*TT + t+1)*DWW + cj] = s0;
            wm [((size_t)(n0+cs+8)*TT + t+1)*DWW + cj] = m1;
            wsd[((size_t)(n0+cs+8)*TT + t+1)*DWW + cj] = s1;
            const int sw = cj >> 3;
            sWf[ cs   *64 + ((sw ^ ( cs   &7))<<3) + (cj&7)] = (char)f2e4m3(w0);
            sWf[(cs+8)*64 + ((sw ^ ((cs+8)&7))<<3) + (cj&7)] = (char)f2e4m3(w1);
        }
        if (tid < 16){
            float mx = -1e30f;
            #pragma unroll
            for (int m = 0; m < 16; m++) mx = fmaxf(mx, sL[tid*20+m]);
            float ss = 0.f;
            float ex[16];
            #pragma unroll
            for (int m = 0; m < 16; m++){ ex[m] = __expf(sL[tid*20+m]-mx); ss += ex[m]; }
            float inv = 0.0625f/ss;   // fold 1/16 (fp8 weights pre-scaled x16)
            #pragma unroll
            for (int m = 0; m < 16; m++) sAl[tid*17+m] = ex[m]*inv;
        }
        if (t < TT-2) issue_inputs(t+1);
        LWAIT(); BAR();

        // ============ phase D: fp8 G5, 8 mixture pairs, hoisted fp8 B-frags
        long bz0 = *(const long*)&sZf[smp*128 + (((0*4+q) ^ sx7)<<3)];
        long bz1 = *(const long*)&sZf[smp*128 + (((1*4+q) ^ sx7)<<3)];
        long bz2 = *(const long*)&sZf[smp*128 + (((2*4+q) ^ sx7)<<3)];
        long bz3 = *(const long*)&sZf[smp*128 + (((3*4+q) ^ sx7)<<3)];
        long bu8 = *(const long*)&sUf[t&1][smp*32 + ((q ^ (smp&3))<<3)];
        long bw80 = *(const long*)&sWf[smp*64 + ((q ^ sx7)<<3)];
        long bw81 = *(const long*)&sWf[smp*64 + (((4+q) ^ sx7)<<3)];
        f32x4 zac = {0.f,0.f,0.f,0.f};
        #pragma unroll
        for (int j = 0; j < 8; j++){
            const int bf = j & 1;
            VWAIT();                               // c(4+j) landed
            f32x4 d = {0.f,0.f,0.f,0.f}, e = {0.f,0.f,0.f,0.f};
            d = MF8(AF8(bf,0), bz0, d); e = MF8(AF8(bf,1), bz1, e);
            d = MF8(AF8(bf,2), bz2, d); e = MF8(AF8(bf,3), bz3, e);
            d = MF8(AF8(bf,4), bu8, d); e = MF8(AF8(bf,5), bw80, e);
            d = MF8(AF8(bf,6), bw81, d);
            f32x4 g = {0.f,0.f,0.f,0.f}, h = {0.f,0.f,0.f,0.f};
            g = MF8(AF8(bf,7), bz0, g);  h = MF8(AF8(bf,8), bz1, h);
            g = MF8(AF8(bf,9), bz2, g);  h = MF8(AF8(bf,10), bz3, h);
            g = MF8(AF8(bf,11), bu8, g); h = MF8(AF8(bf,12), bw80, h);
            g = MF8(AF8(bf,13), bw81, g);
            ISSUE_CHUNK(6+j);                      // j=6 -> c0', j=7 -> c1'
            const float al0 = sAl[smp*17 + 2*j];
            const float al1 = sAl[smp*17 + 2*j + 1];
            f32x4 s0 = d + e, s1 = g + h;
            zac[0] += al0*s0[0] + al1*s1[0];
            zac[1] += al0*s0[1] + al1*s1[1];
            zac[2] += al0*s0[2] + al1*s1[2];
            zac[3] += al0*s0[3] + al1*s1[3];
        }
        LWAIT(); BAR();                            // all reads of z/u/w done

        // epilogue: z_{t+1} -> sZr (bf16), sZf (fp8), zb (f32)
        {
            const int slotz = 2*wv + (q>>1);
            const int basez = smp*128 + ((slotz ^ sx7)<<3) + (q&1)*4;
            *(unsigned int*)&sZr[basez]   = f2bf(zac[0]) | (f2bf(zac[1])<<16);
            *(unsigned int*)&sZr[basez+2] = f2bf(zac[2]) | (f2bf(zac[3])<<16);
            unsigned int p8 = f2e4m3(zac[0]) | (f2e4m3(zac[1])<<8)
                            | (f2e4m3(zac[2])<<16) | (f2e4m3(zac[3])<<24);
            *(unsigned int*)&sZf[smp*128 + ((slotz ^ sx7)<<3) + (q&1)*4] = p8;
            float4 st = {zac[0], zac[1], zac[2], zac[3]};
            *(float4*)&zb[((size_t)(n0+smp)*TT + t+1)*DZZ + wv*16 + q*4] = st;
        }
        LWAIT(); BAR();
    }
    asm volatile("s_waitcnt vmcnt(0) lgkmcnt(0)" ::: "memory");
    #undef ISSUE_CHUNK
    #undef AFRAG
    #undef AF8
    #undef BX
    #undef BZ
    #undef BH1
    #undef BH2
}

// ---------------------------------------------------------------------------
// K5: reconstruction + squared-error (unchanged)
// ---------------------------------------------------------------------------
__global__ __launch_bounds__(256) void k_ob(const float* __restrict__ X,
        const float* __restrict__ zb,
        const float* __restrict__ b1, const float* __restrict__ b2,
        const unsigned short* __restrict__ blob, float* __restrict__ acc)
{
    __shared__ __align__(16) char  sW[2][32768];
    __shared__ __align__(16) float sZ[32*128];
    __shared__ __align__(16) float sH[32*128];
    __shared__ float redb[4];
    const int tid = threadIdx.x;
    const size_t row0 = (size_t)blockIdx.x * 32;
    const int g = tid & 127, rh = tid >> 7;
    for (int l = tid; l < 32*128; l += 256)
        sZ[l] = zb[(row0 + (size_t)(l >> 7))*DZZ + (l & 127)];
    stage32k((const char*)blob, sW[0], tid);
    asm volatile("s_waitcnt vmcnt(0)" ::: "memory");
    __syncthreads();
    stage32k((const char*)blob + 32768, sW[1], tid);
    float h[16];
    #pragma unroll
    for (int r = 0; r < 16; r++) h[r] = 0.f;
    #pragma unroll 4
    for (int s = 0; s < 16; s++){
        const uint32_t* wp = (const uint32_t*)(sW[0] + g*256 + ((s ^ (g & 7)) << 4));
        float wv[8];
        #pragma unroll
        for (int d = 0; d < 4; d++){
            uint32_t w2 = wp[d];
            wv[2*d]   = __uint_as_float(w2 << 16);
            wv[2*d+1] = __uint_as_float(w2 & 0xffff0000u);
        }
        #pragma unroll
        for (int r = 0; r < 16; r++){
            const float* ip = &sZ[(rh*16+r)*128 + s*8];
            float4 u0 = *(const float4*)ip;
            float4 u1 = *(const float4*)(ip+4);
            h[r] = fmaf(wv[0],u0.x, fmaf(wv[1],u0.y, fmaf(wv[2],u0.z, fmaf(wv[3],u0.w, h[r]))));
            h[r] = fmaf(wv[4],u1.x, fmaf(wv[5],u1.y, fmaf(wv[6],u1.z, fmaf(wv[7],u1.w, h[r]))));
        }
    }
    {
        const float bb1 = b1[g];
        #pragma unroll
        for (int r = 0; r < 16; r++){
            h[r] = fmaxf(h[r] + bb1, 0.f);
            sH[(rh*16+r)*128 + g] = h[r];
        }
    }
    asm volatile("s_waitcnt vmcnt(0)" ::: "memory");
    __syncthreads();
    float errs = 0.f;
    stage32k((const char*)blob + 65536, sW[0], tid);
    #pragma unroll 1
    for (int cb = 0; cb < 2; cb++){
        const char* wt = cb ? (const char*)sW[0] : (const char*)sW[1];
        float a2[16];
        #pragma unroll
        for (int r = 0; r < 16; r++) a2[r] = 0.f;
        #pragma unroll 4
        for (int s = 0; s < 16; s++){
            const uint32_t* wp = (const uint32_t*)(wt + g*256 + ((s ^ (g & 7)) << 4));
            float wv[8];
            #pragma unroll
            for (int d = 0; d < 4; d++){
                uint32_t w2 = wp[d];
                wv[2*d]   = __uint_as_float(w2 << 16);
                wv[2*d+1] = __uint_as_float(w2 & 0xffff0000u);
            }
            #pragma unroll
            for (int r = 0; r < 16; r++){
                const float* ip = &sH[(rh*16+r)*128 + s*8];
                float4 u0 = *(const float4*)ip;
                float4 u1 = *(const float4*)(ip+4);
                a2[r] = fmaf(wv[0],u0.x, fmaf(wv[1],u0.y, fmaf(wv[2],u0.z, fmaf(wv[3],u0.w, a2[r]))));
                a2[r] = fmaf(wv[4],u1.x, fmaf(wv[5],u1.y, fmaf(wv[6],u1.z, fmaf(wv[7],u1.w, a2[r]))));
            }
        }
        const float bb2 = b2[cb*128 + g];
        #pragma unroll
        for (int r = 0; r < 16; r++){
            float xr = a2[r] + bb2;
            float xv = X[(row0 + rh*16 + r)*DXX + cb*128 + g];
            float e = xv - xr;
            errs += e*e;
        }
        if (cb == 0){
            asm volatile("s_waitcnt vmcnt(0)" ::: "memory");
            __syncthreads();
        }
    }
    for (int o = 32; o > 0; o >>= 1) errs += __shfl_down(errs, o);
    if ((tid & 63) == 0) redb[tid >> 6] = errs;
    __syncthreads();
    if (tid == 0) atomicAdd(acc, redb[0]+redb[1]+redb[2]+redb[3]);
}

// ---------------------------------------------------------------------------
// K6: KL partial sums (unchanged)
// ---------------------------------------------------------------------------
__global__ __launch_bounds__(256) void k_kl(const float* __restrict__ wm,
                                            const float* __restrict__ wsd,
                                            float* __restrict__ acc)
{
    __shared__ float red[3][4];
    const int tid = threadIdx.x;
    const size_t base = (size_t)blockIdx.x * 4096 + tid;
    float s2 = 0.f, s3 = 0.f, s4 = 0.f;
    #pragma unroll
    for (int it = 0; it < 16; it++){
        size_t i = base + (size_t)it*256;
        float sd = wsd[i], mv = wm[i];
        s2 += sd; s3 += mv*mv; s4 += __logf(sd);
    }
    for (int o = 32; o > 0; o >>= 1){
        s2 += __shfl_down(s2, o); s3 += __shfl_down(s3, o); s4 += __shfl_down(s4, o);
    }
    if ((tid & 63) == 0){ int w = tid >> 6; red[0][w]=s2; red[1][w]=s3; red[2][w]=s4; }
    __syncthreads();
    if (tid == 0) atomicAdd(acc+1, red[0][0]+red[0][1]+red[0][2]+red[0][3]);
    if (tid == 1) atomicAdd(acc+2, red[1][0]+red[1][1]+red[1][2]+red[1][3]);
    if (tid == 2) atomicAdd(acc+3, red[2][0]+red[2][1]+red[2][2]+red[2][3]);
}

__global__ void k_final(const float* __restrict__ acc, float* __restrict__ out)
{
    if (threadIdx.x == 0 && blockIdx.x == 0){
        const double LOG2PI = 1.8378770664093453;
        double logpx_c = 0.5 * (double)NB * TT * DXX * LOG2PI;
        double kl = 0.5 * ((double)acc[1] + (double)acc[2]
                           - (double)NB*TT*DWW - (double)acc[3]);
        out[0] = (float)(0.5*(double)acc[0] + logpx_c + kl);
    }
}

// ---------------------------------------------------------------------------
extern "C" void kernel_launch(void* const* d_in, const int* in_sizes, int n_in,
                              void* d_out, int out_size, void* d_ws, size_t ws_size,
                              hipStream_t stream)
{
    (void)in_sizes; (void)n_in; (void)out_size; (void)ws_size;
    const float* x      = (const float*)d_in[0];
    const float* u      = (const float*)d_in[1];
    const float* eps1   = (const float*)d_in[2];
    const float* eps    = (const float*)d_in[3];
    const float* fw_Wih = (const float*)d_in[4];
    const float* fw_Whh = (const float*)d_in[5];
    const float* fw_b   = (const float*)d_in[6];
    const float* bw_Wih = (const float*)d_in[7];
    const float* bw_b   = (const float*)d_in[9];
    const float* i1w = (const float*)d_in[10];
    const float* i1b = (const float*)d_in[11];
    const float* i2w = (const float*)d_in[12];
    const float* i2b = (const float*)d_in[13];
    const float* z1w = (const float*)d_in[14];
    const float* z1b = (const float*)d_in[15];
    const float* z2w = (const float*)d_in[16];
    const float* z2b = (const float*)d_in[17];
    const float* wp_w1 = (const float*)d_in[18];
    const float* wp_b1 = (const float*)d_in[19];
    const float* wp_w2 = (const float*)d_in[20];
    const float* wp_b2 = (const float*)d_in[21];
    const float* vp_w1 = (const float*)d_in[22];
    const float* vp_b1 = (const float*)d_in[23];
    const float* vp_w2 = (const float*)d_in[24];
    const float* vp_b2 = (const float*)d_in[25];
    const float* ob_w1 = (const float*)d_in[26];
    const float* ob_b1 = (const float*)d_in[27];
    const float* ob_w2 = (const float*)d_in[28];
    const float* ob_b2 = (const float*)d_in[29];
    const float* Amat  = (const float*)d_in[30];
    const float* Bmat  = (const float*)d_in[31];
    const float* Cmat  = (const float*)d_in[32];
    float* out = (float*)d_out;

    unsigned short* xgb = (unsigned short*)d_ws;                      // N*T*4H bf16
    float* h0  = (float*)(xgb + (size_t)NB*TT*G4);
    float* zb  = h0  + (size_t)NB*HHH;
    float* wm  = zb  + (size_t)NB*TT*DZZ;
    float* wsd = wm  + (size_t)NB*TT*DWW;
    float* acc = wsd + (size_t)NB*TT*DWW;
    unsigned short* blstm = (unsigned short*)(acc + 64);              // 4 tiles
    unsigned short* bob   = blstm + (size_t)4*16384;                  // 3 tiles
    unsigned short* bfrag = bob   + (size_t)3*16384;                  // 8 x 180 bf16 tiles
    unsigned short* bfragx= bfrag + (size_t)1440*512;                 // 256 frag tiles
    unsigned char*  bfrag8= (unsigned char*)(bfragx + (size_t)256*512); // 8 x 64 x 7168 fp8
    unsigned short* IX    = (unsigned short*)(bfrag8 + (size_t)512*7168);
    unsigned short* IU    = IX + (size_t)32*127*4096;
    unsigned short* IE    = IU + (size_t)32*127*512;
    unsigned char*  IUf   = (unsigned char*)(IE + (size_t)32*127*1024);

    hipMemsetAsync(acc, 0, 4*sizeof(float), stream);

    k_prep2<<<1440, 256, 0, stream>>>(wp_w1, wp_w2, vp_w1, vp_w2, bfrag);
    k_prep8<<<512, 256, 0, stream>>>(Amat, Bmat, Cmat, bfrag8);
    k_prep_xg<<<256, 256, 0, stream>>>(fw_Wih, bfragx);
    k_prep_lo<<<7, 256, 0, stream>>>(fw_Whh, ob_w1, ob_w2, blstm, bob);
    k_prep_in<<<dim3(32,127), 256, 0, stream>>>(x, u, eps, IX, IU, IE, IUf);
    k_xg2 <<<NB*TT/16, 512, 0, stream>>>(x, bfragx, fw_b, xgb);
    k_lstm<<<NB/2, 256, 0, stream>>>(xgb, blstm, h0);
    k_init<<<NB/4, 256, 0, stream>>>(x, bw_Wih, bw_b, i1w, i1b, i2w, i2b,
                                     z1w, z1b, z2w, z2b, eps1, h0, zb, wm, wsd);
    k_scan<<<32, 512, 0, stream>>>(wp_b1, wp_b2, vp_b1, vp_b2,
                                   (const short*)bfrag, bfrag8, IX, IU, IE, IUf,
                                   zb, wm, wsd);
    k_ob  <<<NB*TT/32, 256, 0, stream>>>(x, zb, ob_b1, ob_b2, bob, acc);
    k_kl  <<<NB*TT*DWW/4096, 256, 0, stream>>>(wm, wsd, acc);
    k_final<<<1, 64, 0, stream>>>(acc, out);
}

// Round 11
// 2851.680 us; speedup vs baseline: 1.0485x; 1.0485x over previous
//
#include <hip/hip_runtime.h>
#include <stdint.h>
#include <math.h>

#define NB  512
#define TT  128
#define DXX 256
#define DUU 32
#define DZZ 128
#define DWW 64
#define MMM 16
#define HHH 128
#define G4  512   // 4*H

typedef __attribute__((ext_vector_type(8))) short bf16x8;
typedef __attribute__((ext_vector_type(4))) float f32x4;
#define MFMA(a,b,c) __builtin_amdgcn_mfma_f32_16x16x32_bf16(a,b,c,0,0,0)
#define MF8(a,b,c)  __builtin_amdgcn_mfma_f32_16x16x32_fp8_fp8(a,b,c,0,0,0)

__device__ __forceinline__ float sigf(float x){ return 1.f/(1.f+__expf(-x)); }
__device__ __forceinline__ float fast_tanh(float x){
    float e = __expf(2.f*x);
    return 1.f - 2.f/(e + 1.f);
}
__device__ __forceinline__ unsigned int f2bf(float f){
    uint32_t u = __float_as_uint(f);
    uint32_t r = (u + 0x7fffu + ((u >> 16) & 1u)) >> 16;
    return r;
}
__device__ __forceinline__ float bf2f(unsigned short u){
    return __uint_as_float(((uint32_t)u) << 16);
}
// OCP e4m3fn encode, RNE, subnormal-correct, clamp to +-448
__device__ __forceinline__ unsigned int f2e4m3(float f){
    uint32_t u = __float_as_uint(f);
    uint32_t s = (u >> 24) & 0x80u;
    uint32_t a = u & 0x7fffffffu;
    if (a >= 0x43e00000u) return s | 0x7eu;
    int exp = (int)(a >> 23) - 127;
    uint32_t mant = a & 0x7fffffu;
    uint32_t code;
    if (exp >= -6){
        uint32_t keep = ((uint32_t)(exp + 7) << 3) | (mant >> 20);
        uint32_t rem = mant & 0xfffffu;
        if (rem > 0x80000u || (rem == 0x80000u && (keep & 1))) keep++;
        code = keep;
        if (code >= 0x7fu) code = 0x7eu;
    } else {
        int rs = 14 - exp;
        if (rs >= 33) return s;
        uint64_t full = (uint64_t)(mant | 0x800000u);
        uint64_t q = full >> rs;
        uint64_t rem = full & (((uint64_t)1 << rs) - 1);
        uint64_t half = (uint64_t)1 << (rs - 1);
        if (rem > half || (rem == half && (q & 1))) q++;
        code = (uint32_t)q;
    }
    return s | code;
}

__device__ __forceinline__ void stage1k(const void* gsrc, void* ldst, int ln)
{
    __builtin_amdgcn_global_load_lds(
        (const __attribute__((address_space(1))) void*)((const char*)gsrc + ln*16),
        (__attribute__((address_space(3))) void*)ldst, 16, 0, 0);
}
__device__ __forceinline__ void stage32k(const void* gsrc, void* ldst, int tid)
{
    const char* g = (const char*)gsrc;
    char* l = (char*)ldst;
    const int lane = tid & 63;
    const int wv   = tid >> 6;
    #pragma unroll
    for (int it = 0; it < 8; it++){
        const int off = it*4096 + wv*1024;
        __builtin_amdgcn_global_load_lds(
            (const __attribute__((address_space(1))) void*)(g + off + lane*16),
            (__attribute__((address_space(3))) void*)(l + off),
            16, 0, 0);
    }
}

// ===========================================================================
// k_prep8b: ALL scan weights as fp8 frags (x16 scale), per-wave LINEAR blob.
// Per wave: 128 frags x 512B = 64KB = 8 chunks x 8KB. frag f (col=wv*16+
// (lane&15), kk=(lane>>4)*8+j):
//   f<4 : G1z wp_w1[col][256+f*32+kk]
//   f<8 : G3z vp_w1[col][(f-4)*32+kk]
//   f<12: G2  wp_w2[col][(f-8)*32+kk]
//   f<16: G4  (wv0 only) vp_w2[col&15][(f-12)*32+kk]
//   else: ABC fi=f-16: m=fi/7, kt=fi%7, k=kt*32+kk over [z128|u32|w64]
// ===========================================================================
__global__ __launch_bounds__(256) void k_prep8b(
    const float* __restrict__ wp_w1, const float* __restrict__ wp_w2,
    const float* __restrict__ vp_w1, const float* __restrict__ vp_w2,
    const float* __restrict__ Amat,  const float* __restrict__ Bmat,
    const float* __restrict__ Cmat,  unsigned char* __restrict__ frag8)
{
    const int wv = blockIdx.x >> 3, c = blockIdx.x & 7;
    unsigned char* dst = frag8 + (size_t)(wv*8 + c)*8192;
    for (int d = threadIdx.x*4; d < 8192; d += 1024){
        uint32_t pk = 0;
        #pragma unroll
        for (int i = 0; i < 4; i++){
            const int B = d + i;
            const int f = 16*c + (B >> 9), r = B & 511;
            const int lane = r >> 3, jj = r & 7;
            const int col = wv*16 + (lane & 15);
            const int kk = (lane >> 4)*8 + jj;
            float v = 0.f;
            if (f < 4)       v = wp_w1[(size_t)col*416 + 256 + f*32 + kk];
            else if (f < 8)  v = vp_w1[(size_t)col*160 + (f-4)*32 + kk];
            else if (f < 12) v = wp_w2[(size_t)col*128 + (f-8)*32 + kk];
            else if (f < 16){ if (wv == 0) v = vp_w2[(size_t)(col&15)*128 + (f-12)*32 + kk]; }
            else {
                const int fi = f-16, m = fi/7, kt = fi%7;
                const int k = kt*32 + kk;
                if (k < 128)      v = Amat[((size_t)m*128 + col)*128 + k];
                else if (k < 160) v = Bmat[((size_t)m*128 + col)*32 + (k-128)];
                else              v = Cmat[((size_t)m*128 + col)*64 + (k-160)];
            }
            pk |= f2e4m3(v * 16.f) << (8*i);
        }
        *(uint32_t*)(dst + d) = pk;
    }
}

// ===========================================================================
// k_prep_p: bf16 A-frags for k_pxu. ct=blk/10, f=blk%10 (80 tiles of 1KB):
//   f<8: wp_w1[col][f*32+kk] (x-part); f==8: wp_w1[col][384+kk] (u);
//   f==9: vp_w1[col][128+kk] (u)
// ===========================================================================
__global__ __launch_bounds__(256) void k_prep_p(
    const float* __restrict__ wp_w1, const float* __restrict__ vp_w1,
    unsigned short* __restrict__ fragP)
{
    const int ct = blockIdx.x / 10, f = blockIdx.x % 10;
    unsigned short* dst = fragP + (size_t)blockIdx.x*512;
    for (int e = threadIdx.x; e < 512; e += 256){
        const int lane = e >> 3, j = e & 7;
        const int col = 16*ct + (lane & 15);
        const int kk = (lane >> 4)*8 + j;
        float v;
        if (f < 8)      v = wp_w1[(size_t)col*416 + f*32 + kk];
        else if (f == 8) v = wp_w1[(size_t)col*416 + 384 + kk];
        else             v = vp_w1[(size_t)col*160 + 128 + kk];
        dst[e] = (unsigned short)f2bf(v);
    }
}

// ---------------------------------------------------------------------------
// k_prep_xg / k_prep_lo (unchanged)
// ---------------------------------------------------------------------------
__global__ __launch_bounds__(256) void k_prep_xg(const float* __restrict__ Wih,
                                                 unsigned short* __restrict__ fragx)
{
    const int T = blockIdx.x;
    const int ct = T >> 3, kt = T & 7;
    unsigned short* dst = fragx + (size_t)T*512;
    for (int e = threadIdx.x; e < 512; e += 256){
        const int lane = e >> 3, j = e & 7;
        const int m16 = lane & 15, kq = lane >> 4;
        const int kk = 8*kq + j;
        float v = Wih[(size_t)(16*ct + m16)*DXX + 32*kt + kk];
        dst[e] = (unsigned short)f2bf(v);
    }
}

__global__ __launch_bounds__(256) void k_prep_lo(
    const float* __restrict__ Whh,
    const float* __restrict__ ob_w1, const float* __restrict__ ob_w2,
    unsigned short* __restrict__ blstm, unsigned short* __restrict__ bob)
{
    const int tile = blockIdx.x;
    unsigned short* dst; int lt;
    if (tile < 4){ dst = blstm + (size_t)tile*16384; lt = 1; }
    else { dst = bob + (size_t)(tile-4)*16384; lt = 2; }
    for (int e = threadIdx.x; e < 16384; e += 256){
        const int g = e >> 7, p = e & 127;
        const int s = p >> 3, j = p & 7;
        const int k = ((s ^ (g & 7)) << 3) | j;
        float v;
        if (lt == 1) v = Whh[(size_t)(tile*128 + g)*128 + k];
        else {
            const int tt = tile - 4;
            if (tt == 0) v = ob_w1[g*128 + k];
            else         v = ob_w2[(size_t)((tt-1)*128 + g)*128 + k];
        }
        dst[e] = (unsigned short)f2bf(v);
    }
}

// ===========================================================================
// k_prep_in: bf16 eps image (IE) + fp8 u image (IUf) only
// ===========================================================================
__global__ __launch_bounds__(256) void k_prep_in(
    const float* __restrict__ U, const float* __restrict__ EPS,
    unsigned short* __restrict__ IE, unsigned char* __restrict__ IUf)
{
    const int b  = blockIdx.x;
    const int tt = blockIdx.y;
    const int n0 = b*16;
    unsigned short* de = IE + ((size_t)b*127 + tt)*1024;
    for (int h = threadIdx.x; h < 1024; h += 256){
        const int e2 = h >> 9, l = (h >> 3) & 63, j = h & 7;
        const int r = 8*e2 + (l >> 3);
        de[h] = (unsigned short)f2bf(EPS[((size_t)(n0+r)*TT + tt+1)*DWW + (l&7)*8 + j]);
    }
    unsigned char* df = IUf + ((size_t)b*127 + tt)*512;
    for (int h = threadIdx.x; h < 512; h += 256){
        const int smp = h >> 5, sp = (h >> 3) & 3, j = h & 7;
        const int ud = ((sp ^ (smp & 3))*8) + j;
        df[h] = (unsigned char)f2e4m3(U[((size_t)(n0+smp)*TT + tt)*DUU + ud]);
    }
}

// ===========================================================================
// k_pxu: Px[b,t] = wp_w1_x . x_{t+1} + wp_w1_u . u_t + wp_b1
//        PL[b,t] = vp_w1_u . u_t + vp_b1
// Output bf16 images in scan-LDS layout (2048 hw per (b,t) each).
// ===========================================================================
__global__ __launch_bounds__(512) void k_pxu(
    const float* __restrict__ X, const float* __restrict__ U,
    const float* __restrict__ wp_b1, const float* __restrict__ vp_b1,
    const unsigned short* __restrict__ fragP,
    unsigned short* __restrict__ IPx, unsigned short* __restrict__ IPL)
{
    __shared__ __align__(16) short sXl[16*256];
    __shared__ __align__(16) short sUl[16*32];
    const int tid = threadIdx.x;
    const int b = blockIdx.x, t = blockIdx.y;
    const int n0 = b*16;
    const int wv = tid >> 6, ln = tid & 63;
    const int rr = ln & 15, q = ln >> 4;
    const int sx7 = rr & 7;
    {
        const int r = tid >> 5, sl = tid & 31;
        const float* xp = &X[((size_t)(n0+r)*TT + t+1)*DXX + sl*8];
        float4 a0 = *(const float4*)xp;
        float4 a1 = *(const float4*)(xp+4);
        int4 pk;
        pk.x = f2bf(a0.x) | (f2bf(a0.y)<<16);
        pk.y = f2bf(a0.z) | (f2bf(a0.w)<<16);
        pk.z = f2bf(a1.x) | (f2bf(a1.y)<<16);
        pk.w = f2bf(a1.z) | (f2bf(a1.w)<<16);
        *(int4*)&sXl[r*256 + ((sl ^ (r&7))<<3)] = pk;
    }
    {
        const int r = tid >> 5, cc = tid & 31;
        sUl[r*32 + (((cc>>3) ^ (r&3))<<3) + (cc&7)] =
            (unsigned short)f2bf(U[((size_t)(n0+r)*TT + t)*DUU + cc]);
    }
    __syncthreads();
    const short* pA = (const short*)fragP + (size_t)wv*10*512 + ln*8;
    f32x4 d = {0.f,0.f,0.f,0.f};
    #pragma unroll
    for (int kt = 0; kt < 8; kt++){
        bf16x8 a = *(const bf16x8*)(pA + kt*512);
        bf16x8 bx = *(const bf16x8*)&sXl[rr*256 + (((4*kt+q) ^ sx7)<<3)];
        d = MFMA(a, bx, d);
    }
    bf16x8 bu = *(const bf16x8*)&sUl[rr*32 + ((q ^ (rr&3))<<3)];
    d = MFMA(*(const bf16x8*)(pA + 8*512), bu, d);
    f32x4 dl = {0.f,0.f,0.f,0.f};
    dl = MFMA(*(const bf16x8*)(pA + 9*512), bu, dl);
    const f32x4 b1v = *(const f32x4*)&wp_b1[wv*16 + q*4];
    const f32x4 bLv = *(const f32x4*)&vp_b1[wv*16 + q*4];
    d = d + b1v;
    dl = dl + bLv;
    const size_t base = ((size_t)b*127 + t)*2048
                      + rr*128 + (((2*wv + (q>>1)) ^ sx7)<<3) + (q&1)*4;
    uint2 p1, p2;
    p1.x = f2bf(d[0]) | (f2bf(d[1])<<16);
    p1.y = f2bf(d[2]) | (f2bf(d[3])<<16);
    p2.x = f2bf(dl[0]) | (f2bf(dl[1])<<16);
    p2.y = f2bf(dl[2]) | (f2bf(dl[3])<<16);
    *(uint2*)&IPx[base] = p1;
    *(uint2*)&IPL[base] = p2;
}

// ---------------------------------------------------------------------------
// fp32 dense helper (k_init only)
// ---------------------------------------------------------------------------
template<int ACT>
__device__ void dense(const float* __restrict__ W, const float* __restrict__ bias,
                      int C, int K, const float* sIn, int ldi,
                      float* sOut, int ldo, float* sWt)
{
    const int tid = threadIdx.x;
    const int g   = tid & 127;
    const int rq  = tid >> 7;
    const int r0  = 2*rq, r1 = 2*rq+1;
    for (int cb = 0; cb < C; cb += 128){
        float acc0 = 0.f, acc1 = 0.f;
        for (int kb = 0; kb < K; kb += 64){
            const int kw = (K - kb < 64) ? (K - kb) : 64;
            __syncthreads();
            if (kw == 64){
                for (int l = tid; l < 128*64; l += 256){
                    int gg = l >> 6, kk = l & 63;
                    int cx = cb + gg;
                    sWt[gg*65 + kk] = (cx < C) ? W[(size_t)cx*K + kb + kk] : 0.f;
                }
            } else {
                for (int l = tid; l < 128*32; l += 256){
                    int gg = l >> 5, kk = l & 31;
                    int cx = cb + gg;
                    sWt[gg*65 + kk] = (cx < C) ? W[(size_t)cx*K + kb + kk] : 0.f;
                }
            }
            __syncthreads();
            const float* ip0 = sIn + r0*ldi + kb;
            const float* ip1 = sIn + r1*ldi + kb;
            const float* wp  = sWt + g*65;
            #pragma unroll 8
            for (int k = 0; k < kw; k++){
                float wv = wp[k];
                acc0 += ip0[k]*wv;
                acc1 += ip1[k]*wv;
            }
        }
        int cx = cb + g;
        if (cx < C){
            float b = bias ? bias[cx] : 0.f;
            float v0 = acc0 + b, v1 = acc1 + b;
            if (ACT == 1){ v0 = fmaxf(v0, 0.f); v1 = fmaxf(v1, 0.f); }
            else if (ACT == 2){ v0 = fast_tanh(v0); v1 = fast_tanh(v1); }
            sOut[r0*ldo + cx] = v0;
            sOut[r1*ldo + cx] = v1;
        }
    }
}

// ---------------------------------------------------------------------------
// K1: xg GEMM (unchanged)
// ---------------------------------------------------------------------------
__global__ __launch_bounds__(512) void k_xg2(const float* __restrict__ X,
                                             const unsigned short* __restrict__ fragx,
                                             const float* __restrict__ bias,
                                             unsigned short* __restrict__ xgb)
{
    __shared__ __align__(16) short sXl[16*256];
    const int tid = threadIdx.x;
    const size_t row0 = (size_t)blockIdx.x * 16;
    const int wv = tid >> 6, ln = tid & 63;
    const int rr = ln & 15, q = ln >> 4;
    const int sx7 = rr & 7;
    {
        const int r = tid >> 5, sl = tid & 31;
        const float* xp = &X[(row0 + r)*DXX + sl*8];
        float4 a0 = *(const float4*)xp;
        float4 a1 = *(const float4*)(xp+4);
        int4 pk;
        pk.x = f2bf(a0.x) | (f2bf(a0.y)<<16);
        pk.y = f2bf(a0.z) | (f2bf(a0.w)<<16);
        pk.z = f2bf(a1.x) | (f2bf(a1.y)<<16);
        pk.w = f2bf(a1.z) | (f2bf(a1.w)<<16);
        *(int4*)&sXl[r*256 + ((sl ^ (r&7))<<3)] = pk;
    }
    __syncthreads();
    #pragma unroll
    for (int ci = 0; ci < 4; ci++){
        const int ct = wv*4 + ci;
        const short* pA = (const short*)fragx + (size_t)(ct*8)*512 + ln*8;
        bf16x8 af[8];
        #pragma unroll
        for (int kt = 0; kt < 8; kt++) af[kt] = *(const bf16x8*)(pA + kt*512);
        f32x4 d = {0.f,0.f,0.f,0.f};
        #pragma unroll
        for (int kt = 0; kt < 8; kt++){
            bf16x8 b = *(const bf16x8*)&sXl[rr*256 + (((4*kt+q) ^ sx7)<<3)];
            d = MFMA(af[kt], b, d);
        }
        const f32x4 bb = *(const f32x4*)&bias[ct*16 + q*4];
        uint2 pk;
        pk.x = f2bf(d[0]+bb[0]) | (f2bf(d[1]+bb[1])<<16);
        pk.y = f2bf(d[2]+bb[2]) | (f2bf(d[3]+bb[3])<<16);
        *(uint2*)&xgb[(row0 + rr)*G4 + ct*16 + q*4] = pk;
    }
}

// ---------------------------------------------------------------------------
// K2: forward LSTM (unchanged)
// ---------------------------------------------------------------------------
__global__ __launch_bounds__(256) void k_lstm(const unsigned short* __restrict__ xgb,
                                              const unsigned short* __restrict__ blob,
                                              float* __restrict__ h0)
{
    __shared__ __align__(16) char sWh[4][32768];
    __shared__ __align__(16) float sHh[2][128];
    const int tid = threadIdx.x;
    const int n0 = blockIdx.x * 2;
    const int g = tid & 127, rh = tid >> 7;
    #pragma unroll
    for (int i = 0; i < 4; i++)
        stage32k((const char*)blob + (size_t)i*32768, sWh[i], tid);
    sHh[tid >> 7][tid & 127] = 0.f;
    float cc = 0.f;
    asm volatile("s_waitcnt vmcnt(0)" ::: "memory");
    __syncthreads();
    const size_t xbase = ((size_t)(n0+rh)*TT)*G4 + g;
    for (int t = 0; t < TT; t++){
        float xv[4];
        #pragma unroll
        for (int ct = 0; ct < 4; ct++) xv[ct] = bf2f(xgb[xbase + (size_t)t*G4 + ct*128]);
        float a[4] = {0.f,0.f,0.f,0.f};
        #pragma unroll
        for (int s = 0; s < 16; s++){
            const float* ip = &sHh[rh][s*8];
            float4 u0 = *(const float4*)ip;
            float4 u1 = *(const float4*)(ip+4);
            float in[8] = {u0.x,u0.y,u0.z,u0.w,u1.x,u1.y,u1.z,u1.w};
            #pragma unroll
            for (int ct = 0; ct < 4; ct++){
                const uint32_t* wp = (const uint32_t*)(sWh[ct] + g*256 + ((s ^ (g & 7)) << 4));
                #pragma unroll
                for (int d = 0; d < 4; d++){
                    uint32_t w2 = wp[d];
                    a[ct] = fmaf(__uint_as_float(w2 << 16),        in[2*d],   a[ct]);
                    a[ct] = fmaf(__uint_as_float(w2 & 0xffff0000u), in[2*d+1], a[ct]);
                }
            }
        }
        __syncthreads();
        float ii = sigf(a[0] + xv[0]);
        float ff = sigf(a[1] + xv[1]);
        float gg = fast_tanh(a[2] + xv[2]);
        float oo = sigf(a[3] + xv[3]);
        cc = ff*cc + ii*gg;
        float hh = oo*fast_tanh(cc);
        sHh[rh][g] = hh;
        __syncthreads();
    }
    h0[(size_t)(n0+rh)*HHH + g] = sHh[rh][g];
}

// ---------------------------------------------------------------------------
// K3: init net (unchanged)
// ---------------------------------------------------------------------------
__global__ __launch_bounds__(256) void k_init(
    const float* __restrict__ X,
    const float* __restrict__ bw_Wih, const float* __restrict__ bw_b,
    const float* __restrict__ i1w, const float* __restrict__ i1b,
    const float* __restrict__ i2w, const float* __restrict__ i2b,
    const float* __restrict__ z1w, const float* __restrict__ z1b,
    const float* __restrict__ z2w, const float* __restrict__ z2b,
    const float* __restrict__ eps1, const float* __restrict__ h0,
    float* __restrict__ zb, float* __restrict__ wm, float* __restrict__ wsd)
{
    __shared__ float sX[4*260];
    __shared__ float sG[4*516];
    __shared__ float sH0[4*260];
    __shared__ float sT[4*132];
    __shared__ float sP[4*132];
    __shared__ float sWt[128*65];
    const int tid = threadIdx.x;
    const int n0  = blockIdx.x * 4;
    for (int l = tid; l < 4*256; l += 256){
        int r = l >> 8, k = l & 255;
        sX[r*260+k] = X[((size_t)(n0+r)*TT + (TT-1))*DXX + k];
    }
    for (int l = tid; l < 4*128; l += 256){
        int r = l >> 7, j = l & 127;
        sH0[r*260+j] = h0[(size_t)(n0+r)*HHH + j];
    }
    dense<0>(bw_Wih, bw_b, 512, 256, sX, 260, sG, 516, sWt);
    __syncthreads();
    for (int l = tid; l < 4*128; l += 256){
        int r = l >> 7, j = l & 127;
        float gi = sG[r*516 + j];
        float gv = sG[r*516 + 256 + j];
        float go = sG[r*516 + 384 + j];
        float c  = sigf(gi)*fast_tanh(gv);
        sH0[r*260 + 128 + j] = sigf(go)*fast_tanh(c);
    }
    dense<1>(i1w, i1b, 128, 256, sH0, 260, sT, 132, sWt);
    dense<0>(i2w, i2b, 128, 128, sT, 132, sP, 132, sWt);
    __syncthreads();
    for (int l = tid; l < 4*64; l += 256){
        int r = l >> 6, j = l & 63;
        float m0 = sP[r*132 + j];
        float s0 = __expf(sP[r*132 + 64 + j]) + 1e-5f;
        float w1 = m0 + s0*eps1[(size_t)(n0+r)*DWW + j];
        wm[((size_t)(n0+r)*TT)*DWW + j]  = m0;
        wsd[((size_t)(n0+r)*TT)*DWW + j] = s0;
        sX[r*68 + j] = w1;
    }
    dense<1>(z1w, z1b, 128, 64, sX, 68, sT, 132, sWt);
    dense<0>(z2w, z2b, 128, 128, sT, 132, sP, 132, sWt);
    __syncthreads();
    for (int l = tid; l < 4*128; l += 256){
        int r = l >> 7, j = l & 127;
        zb[((size_t)(n0+r)*TT)*DZZ + j] = sP[r*132+j];
    }
}

// ===========================================================================
// K4: all-fp8 MFMA scan. 8 chunks/step x 8 slots (vmcnt(8)).
// chunk0 = head (G1z,G3z,G2,G4); chunks 1..7 = ABC (16 frags each, mixture
// partials carried across boundaries). Px/PL precomputed (k_pxu).
// ===========================================================================
#define VWAIT8() do{ asm volatile("s_waitcnt vmcnt(8)" ::: "memory"); \
                    __builtin_amdgcn_sched_barrier(0); }while(0)
#define LWAIT() do{ asm volatile("s_waitcnt lgkmcnt(0)" ::: "memory"); \
                    __builtin_amdgcn_sched_barrier(0); }while(0)
#define BAR()   __builtin_amdgcn_s_barrier()

__global__ __launch_bounds__(512) void k_scan(
    const float* __restrict__ wp_b2, const float* __restrict__ vp_b2,
    const unsigned char* __restrict__ frag8,
    const unsigned short* __restrict__ IPx, const unsigned short* __restrict__ IPL,
    const unsigned short* __restrict__ IE, const unsigned char* __restrict__ IUf,
    float* __restrict__ zb, float* __restrict__ wm, float* __restrict__ wsd)
{
    __shared__ __align__(16) short sRing[65536];   // 8 waves x 2 bufs x 8KB
    __shared__ __align__(16) short sPx[2048];      // bf16 Px image
    __shared__ __align__(16) short sPL[2048];      // bf16 PL image
    __shared__ __align__(16) char  sZf[2048];      // fp8 z
    __shared__ __align__(16) char  sUf[2][512];    // fp8 u dbuf
    __shared__ __align__(16) char  sWf[1024];      // fp8 w
    __shared__ __align__(16) short sEr[1024];      // bf16 eps
    __shared__ __align__(16) char  sH1f[2048];     // fp8 h1
    __shared__ __align__(16) char  sH2f[2048];     // fp8 h2
    __shared__ __align__(16) float sPW[16*132];
    __shared__ __align__(16) float sL [16*20];
    __shared__ float sAl[16*17];

    const int tid = threadIdx.x;
    const int n0  = blockIdx.x * 16;
    const int wv  = tid >> 6;
    const int ln  = tid & 63;
    const int smp = ln & 15, q = ln >> 4;
    const int sx7 = smp & 7;
    char* ringB = (char*)sRing + wv*16384;
    const unsigned char* myblob = frag8 + (size_t)wv*65536;

    const f32x4 bw2 = *(const f32x4*)&wp_b2[wv*16 + q*4];
    f32x4 bv2 = {0.f,0.f,0.f,0.f};
    if (wv == 0) bv2 = *(const f32x4*)&vp_b2[q*4];

    #define ISSUE_CHUNK(cc_) do{ const int c2_ = (cc_) & 7; \
        _Pragma("unroll") \
        for (int k8 = 0; k8 < 8; k8++) \
            stage1k(myblob + (size_t)c2_*8192 + k8*1024, \
                    ringB + (c2_&1)*8192 + k8*1024, ln); }while(0)
    #define AF8(f_) (*(const long*)(ringB + (((f_)>>4)&1)*8192 + ((f_)&15)*512 + ln*8))
    #define BH1F(t_) (*(const long*)&sH1f[smp*128 + (((4*(t_)+q) ^ sx7)<<3)])
    #define BH2F(t_) (*(const long*)&sH2f[smp*128 + (((4*(t_)+q) ^ sx7)<<3)])

    auto issue_inputs = [&](int tt){
        const size_t ib = (size_t)blockIdx.x*127 + tt;
        if (wv < 4) stage1k((const char*)IPx + ib*4096 + wv*1024, (char*)sPx + wv*1024, ln);
        else        stage1k((const char*)IPL + ib*4096 + (wv-4)*1024, (char*)sPL + (wv-4)*1024, ln);
        if (wv == 0)      stage1k((const char*)IE + ib*2048,        (char*)sEr,        ln);
        else if (wv == 1) stage1k((const char*)IE + ib*2048 + 1024, (char*)sEr + 1024, ln);
        else if (wv == 2){ if (ln < 32) stage1k((const char*)IUf + ib*512, sUf[tt&1], ln); }
    };

    // ---- prologue ----
    issue_inputs(0);
    if (tid < 256){
        const int zs = tid >> 4, sl = tid & 15;
        const float* zp = &zb[((size_t)(n0+zs)*TT)*DZZ + sl*8];
        float4 a0 = *(const float4*)zp;
        float4 a1 = *(const float4*)(zp+4);
        uint2 p8;
        p8.x = f2e4m3(a0.x) | (f2e4m3(a0.y)<<8) | (f2e4m3(a0.z)<<16) | (f2e4m3(a0.w)<<24);
        p8.y = f2e4m3(a1.x) | (f2e4m3(a1.y)<<8) | (f2e4m3(a1.z)<<16) | (f2e4m3(a1.w)<<24);
        *(uint2*)&sZf[zs*128 + ((sl ^ (zs&7))<<3)] = p8;
    }
    ISSUE_CHUNK(0);
    ISSUE_CHUNK(1);
    asm volatile("s_waitcnt vmcnt(0)" ::: "memory");
    __builtin_amdgcn_sched_barrier(0);
    LWAIT(); BAR();

    for (int t = 0; t < TT-1; t++){
        long bz0 = *(const long*)&sZf[smp*128 + (((0*4+q) ^ sx7)<<3)];
        long bz1 = *(const long*)&sZf[smp*128 + (((1*4+q) ^ sx7)<<3)];
        long bz2 = *(const long*)&sZf[smp*128 + (((2*4+q) ^ sx7)<<3)];
        long bz3 = *(const long*)&sZf[smp*128 + (((3*4+q) ^ sx7)<<3)];

        // ============ phase A: d1 = G1z.z ; d3 = G3z.z ; pre-read G2/G4
        VWAIT8();                                  // c0 done (newest 8 = c1)
        f32x4 d1a = {0.f,0.f,0.f,0.f}, d1b = {0.f,0.f,0.f,0.f};
        d1a = MF8(AF8(0), bz0, d1a); d1b = MF8(AF8(1), bz1, d1b);
        d1a = MF8(AF8(2), bz2, d1a); d1b = MF8(AF8(3), bz3, d1b);
        f32x4 d3a = {0.f,0.f,0.f,0.f}, d3b = {0.f,0.f,0.f,0.f};
        d3a = MF8(AF8(4), bz0, d3a); d3b = MF8(AF8(5), bz1, d3b);
        d3a = MF8(AF8(6), bz2, d3a); d3b = MF8(AF8(7), bz3, d3b);
        long aG2_0 = AF8(8),  aG2_1 = AF8(9),  aG2_2 = AF8(10), aG2_3 = AF8(11);
        long aG4_0 = AF8(12), aG4_1 = AF8(13), aG4_2 = AF8(14), aG4_3 = AF8(15);
        LWAIT();                                   // buf0 reads complete
        ISSUE_CHUNK(2);                            // overwrite buf0
        {
            const int basep = smp*128 + (((2*wv + (q>>1)) ^ sx7)<<3) + (q&1)*4;
            uint2 pxw = *(const uint2*)&sPx[basep];
            uint2 plw = *(const uint2*)&sPL[basep];
            f32x4 d1 = d1a + d1b, d3 = d3a + d3b;
            float v0 = fast_tanh(d1[0]*0.0625f + bf2f((unsigned short)(pxw.x & 0xffff)));
            float v1 = fast_tanh(d1[1]*0.0625f + bf2f((unsigned short)(pxw.x >> 16)));
            float v2 = fast_tanh(d1[2]*0.0625f + bf2f((unsigned short)(pxw.y & 0xffff)));
            float v3 = fast_tanh(d1[3]*0.0625f + bf2f((unsigned short)(pxw.y >> 16)));
            const int baseh = smp*128 + (((2*wv + (q>>1)) ^ sx7)<<3) + (q&1)*4;
            *(unsigned int*)&sH1f[baseh] =
                f2e4m3(v0) | (f2e4m3(v1)<<8) | (f2e4m3(v2)<<16) | (f2e4m3(v3)<<24);
            float w0 = fmaxf(d3[0]*0.0625f + bf2f((unsigned short)(plw.x & 0xffff)), 0.f);
            float w1 = fmaxf(d3[1]*0.0625f + bf2f((unsigned short)(plw.x >> 16)), 0.f);
            float w2 = fmaxf(d3[2]*0.0625f + bf2f((unsigned short)(plw.y & 0xffff)), 0.f);
            float w3 = fmaxf(d3[3]*0.0625f + bf2f((unsigned short)(plw.y >> 16)), 0.f);
            *(unsigned int*)&sH2f[baseh] =
                f2e4m3(w0) | (f2e4m3(w1)<<8) | (f2e4m3(w2)<<16) | (f2e4m3(w3)<<24);
        }
        LWAIT(); BAR();

        // ============ phase B: d2 = G2.h1 -> sPW ; wv0: d4 = G4.h2 -> sL
        {
            f32x4 d2a = {0.f,0.f,0.f,0.f}, d2b = {0.f,0.f,0.f,0.f};
            d2a = MF8(aG2_0, BH1F(0), d2a); d2b = MF8(aG2_1, BH1F(1), d2b);
            d2a = MF8(aG2_2, BH1F(2), d2a); d2b = MF8(aG2_3, BH1F(3), d2b);
            f32x4 o = (d2a + d2b)*0.0625f + bw2;
            *(f32x4*)&sPW[smp*132 + wv*16 + q*4] = o;
            if (wv == 0){
                f32x4 d4a = {0.f,0.f,0.f,0.f}, d4b = {0.f,0.f,0.f,0.f};
                d4a = MF8(aG4_0, BH2F(0), d4a); d4b = MF8(aG4_1, BH2F(1), d4b);
                d4a = MF8(aG4_2, BH2F(2), d4a); d4b = MF8(aG4_3, BH2F(3), d4b);
                f32x4 o4 = (d4a + d4b)*0.0625f + bv2;
                *(f32x4*)&sL[smp*20 + q*4] = o4;
            }
        }
        LWAIT(); BAR();

        // ============ phase C: w-update + softmax (alpha/16) + input prefetch
        {
            const int cs = wv, cj = ln;
            float e0 = bf2f((unsigned short)sEr[cs*64 + cj]);
            float e1 = bf2f((unsigned short)sEr[(cs+8)*64 + cj]);
            float m0 = sPW[cs*132 + cj];
            float s0 = __expf(sPW[cs*132 + 64 + cj]) + 0.01f;
            float m1 = sPW[(cs+8)*132 + cj];
            float s1 = __expf(sPW[(cs+8)*132 + 64 + cj]) + 0.01f;
            float w0 = m0 + s0*e0;
            float w1 = m1 + s1*e1;
            wm [((size_t)(n0+cs  )*TT + t+1)*DWW + cj] = m0;
            wsd[((size_t)(n0+cs  )*TT + t+1)*DWW + cj] = s0;
            wm [((size_t)(n0+cs+8)*TT + t+1)*DWW + cj] = m1;
            wsd[((size_t)(n0+cs+8)*TT + t+1)*DWW + cj] = s1;
            const int sw = cj >> 3;
            sWf[ cs   *64 + ((sw ^ ( cs   &7))<<3) + (cj&7)] = (char)f2e4m3(w0);
            sWf[(cs+8)*64 + ((sw ^ ((cs+8)&7))<<3) + (cj&7)] = (char)f2e4m3(w1);
        }
        if (tid < 16){
            float mx = -1e30f;
            #pragma unroll
            for (int m = 0; m < 16; m++) mx = fmaxf(mx, sL[tid*20+m]);
            float ss = 0.f;
            float ex[16];
            #pragma unroll
            for (int m = 0; m < 16; m++){ ex[m] = __expf(sL[tid*20+m]-mx); ss += ex[m]; }
            float inv = 0.0625f/ss;
            #pragma unroll
            for (int m = 0; m < 16; m++) sAl[tid*17+m] = ex[m]*inv;
        }
        if (t < TT-2) issue_inputs(t+1);
        LWAIT(); BAR();

        // ============ phase D: ABC walk, chunks 1..7 (16 frags each)
        long bu8 = *(const long*)&sUf[t&1][smp*32 + ((q ^ (smp&3))<<3)];
        long bw80 = *(const long*)&sWf[smp*64 + ((q ^ sx7)<<3)];
        long bw81 = *(const long*)&sWf[smp*64 + (((4+q) ^ sx7)<<3)];
        f32x4 zac = {0.f,0.f,0.f,0.f};
        f32x4 da = {0.f,0.f,0.f,0.f}, db = {0.f,0.f,0.f,0.f};
        #pragma unroll
        for (int c = 1; c <= 7; c++){
            VWAIT8();                              // chunk c done
            #pragma unroll
            for (int pos = 0; pos < 16; pos++){
                const int fi = 16*(c-1) + pos;     // 0..111
                const int m  = fi/7, kt = fi%7;
                long a = AF8(16*c + pos);
                long b;
                if (kt == 0) b = bz0;
                else if (kt == 1) b = bz1;
                else if (kt == 2) b = bz2;
                else if (kt == 3) b = bz3;
                else if (kt == 4) b = bu8;
                else if (kt == 5) b = bw80;
                else b = bw81;
                if (kt & 1) db = MF8(a, b, db);
                else        da = MF8(a, b, da);
                if (kt == 6){
                    const float al = sAl[smp*17 + m];
                    f32x4 s = da + db;
                    zac[0] += al*s[0]; zac[1] += al*s[1];
                    zac[2] += al*s[2]; zac[3] += al*s[3];
                    da = (f32x4){0.f,0.f,0.f,0.f};
                    db = (f32x4){0.f,0.f,0.f,0.f};
                }
            }
            ISSUE_CHUNK(c+2);                      // c=6 -> c0', c=7 -> c1'
        }
        LWAIT(); BAR();                            // all reads of z/u/w done

        // epilogue: z_{t+1} -> sZf (fp8), zb (f32)
        {
            const int slotz = 2*wv + (q>>1);
            unsigned int p8 = f2e4m3(zac[0]) | (f2e4m3(zac[1])<<8)
                            | (f2e4m3(zac[2])<<16) | (f2e4m3(zac[3])<<24);
            *(unsigned int*)&sZf[smp*128 + ((slotz ^ sx7)<<3) + (q&1)*4] = p8;
            float4 st = {zac[0], zac[1], zac[2], zac[3]};
            *(float4*)&zb[((size_t)(n0+smp)*TT + t+1)*DZZ + wv*16 + q*4] = st;
        }
        LWAIT(); BAR();
    }
    asm volatile("s_waitcnt vmcnt(0) lgkmcnt(0)" ::: "memory");
    #undef ISSUE_CHUNK
    #undef AF8
    #undef BH1F
    #undef BH2F
}

// ---------------------------------------------------------------------------
// K5: reconstruction + squared-error (unchanged)
// ---------------------------------------------------------------------------
__global__ __launch_bounds__(256) void k_ob(const float* __restrict__ X,
        const float* __restrict__ zb,
        const float* __restrict__ b1, const float* __restrict__ b2,
        const unsigned short* __restrict__ blob, float* __restrict__ acc)
{
    __shared__ __align__(16) char  sW[2][32768];
    __shared__ __align__(16) float sZ[32*128];
    __shared__ __align__(16) float sH[32*128];
    __shared__ float redb[4];
    const int tid = threadIdx.x;
    const size_t row0 = (size_t)blockIdx.x * 32;
    const int g = tid & 127, rh = tid >> 7;
    for (int l = tid; l < 32*128; l += 256)
        sZ[l] = zb[(row0 + (size_t)(l >> 7))*DZZ + (l & 127)];
    stage32k((const char*)blob, sW[0], tid);
    asm volatile("s_waitcnt vmcnt(0)" ::: "memory");
    __syncthreads();
    stage32k((const char*)blob + 32768, sW[1], tid);
    float h[16];
    #pragma unroll
    for (int r = 0; r < 16; r++) h[r] = 0.f;
    #pragma unroll 4
    for (int s = 0; s < 16; s++){
        const uint32_t* wp = (const uint32_t*)(sW[0] + g*256 + ((s ^ (g & 7)) << 4));
        float wv[8];
        #pragma unroll
        for (int d = 0; d < 4; d++){
            uint32_t w2 = wp[d];
            wv[2*d]   = __uint_as_float(w2 << 16);
            wv[2*d+1] = __uint_as_float(w2 & 0xffff0000u);
        }
        #pragma unroll
        for (int r = 0; r < 16; r++){
            const float* ip = &sZ[(rh*16+r)*128 + s*8];
            float4 u0 = *(const float4*)ip;
            float4 u1 = *(const float4*)(ip+4);
            h[r] = fmaf(wv[0],u0.x, fmaf(wv[1],u0.y, fmaf(wv[2],u0.z, fmaf(wv[3],u0.w, h[r]))));
            h[r] = fmaf(wv[4],u1.x, fmaf(wv[5],u1.y, fmaf(wv[6],u1.z, fmaf(wv[7],u1.w, h[r]))));
        }
    }
    {
        const float bb1 = b1[g];
        #pragma unroll
        for (int r = 0; r < 16; r++){
            h[r] = fmaxf(h[r] + bb1, 0.f);
            sH[(rh*16+r)*128 + g] = h[r];
        }
    }
    asm volatile("s_waitcnt vmcnt(0)" ::: "memory");
    __syncthreads();
    float errs = 0.f;
    stage32k((const char*)blob + 65536, sW[0], tid);
    #pragma unroll 1
    for (int cb = 0; cb < 2; cb++){
        const char* wt = cb ? (const char*)sW[0] : (const char*)sW[1];
        float a2[16];
        #pragma unroll
        for (int r = 0; r < 16; r++) a2[r] = 0.f;
        #pragma unroll 4
        for (int s = 0; s < 16; s++){
            const uint32_t* wp = (const uint32_t*)(wt + g*256 + ((s ^ (g & 7)) << 4));
            float wv[8];
            #pragma unroll
            for (int d = 0; d < 4; d++){
                uint32_t w2 = wp[d];
                wv[2*d]   = __uint_as_float(w2 << 16);
                wv[2*d+1] = __uint_as_float(w2 & 0xffff0000u);
            }
            #pragma unroll
            for (int r = 0; r < 16; r++){
                const float* ip = &sH[(rh*16+r)*128 + s*8];
                float4 u0 = *(const float4*)ip;
                float4 u1 = *(const float4*)(ip+4);
                a2[r] = fmaf(wv[0],u0.x, fmaf(wv[1],u0.y, fmaf(wv[2],u0.z, fmaf(wv[3],u0.w, a2[r]))));
                a2[r] = fmaf(wv[4],u1.x, fmaf(wv[5],u1.y, fmaf(wv[6],u1.z, fmaf(wv[7],u1.w, a2[r]))));
            }
        }
        const float bb2 = b2[cb*128 + g];
        #pragma unroll
        for (int r = 0; r < 16; r++){
            float xr = a2[r] + bb2;
            float xv = X[(row0 + rh*16 + r)*DXX + cb*128 + g];
            float e = xv - xr;
            errs += e*e;
        }
        if (cb == 0){
            asm volatile("s_waitcnt vmcnt(0)" ::: "memory");
            __syncthreads();
        }
    }
    for (int o = 32; o > 0; o >>= 1) errs += __shfl_down(errs, o);
    if ((tid & 63) == 0) redb[tid >> 6] = errs;
    __syncthreads();
    if (tid == 0) atomicAdd(acc, redb[0]+redb[1]+redb[2]+redb[3]);
}

// ---------------------------------------------------------------------------
// K6: KL partial sums (unchanged)
// ---------------------------------------------------------------------------
__global__ __launch_bounds__(256) void k_kl(const float* __restrict__ wm,
                                            const float* __restrict__ wsd,
                                            float* __restrict__ acc)
{
    __shared__ float red[3][4];
    const int tid = threadIdx.x;
    const size_t base = (size_t)blockIdx.x * 4096 + tid;
    float s2 = 0.f, s3 = 0.f, s4 = 0.f;
    #pragma unroll
    for (int it = 0; it < 16; it++){
        size_t i = base + (size_t)it*256;
        float sd = wsd[i], mv = wm[i];
        s2 += sd; s3 += mv*mv; s4 += __logf(sd);
    }
    for (int o = 32; o > 0; o >>= 1){
        s2 += __shfl_down(s2, o); s3 += __shfl_down(s3, o); s4 += __shfl_down(s4, o);
    }
    if ((tid & 63) == 0){ int w = tid >> 6; red[0][w]=s2; red[1][w]=s3; red[2][w]=s4; }
    __syncthreads();
    if (tid == 0) atomicAdd(acc+1, red[0][0]+red[0][1]+red[0][2]+red[0][3]);
    if (tid == 1) atomicAdd(acc+2, red[1][0]+red[1][1]+red[1][2]+red[1][3]);
    if (tid == 2) atomicAdd(acc+3, red[2][0]+red[2][1]+red[2][2]+red[2][3]);
}

__global__ void k_final(const float* __restrict__ acc, float* __restrict__ out)
{
    if (threadIdx.x == 0 && blockIdx.x == 0){
        const double LOG2PI = 1.8378770664093453;
        double logpx_c = 0.5 * (double)NB * TT * DXX * LOG2PI;
        double kl = 0.5 * ((double)acc[1] + (double)acc[2]
                           - (double)NB*TT*DWW - (double)acc[3]);
        out[0] = (float)(0.5*(double)acc[0] + logpx_c + kl);
    }
}

// ---------------------------------------------------------------------------
extern "C" void kernel_launch(void* const* d_in, const int* in_sizes, int n_in,
                              void* d_out, int out_size, void* d_ws, size_t ws_size,
                              hipStream_t stream)
{
    (void)in_sizes; (void)n_in; (void)out_size; (void)ws_size;
    const float* x      = (const float*)d_in[0];
    const float* u      = (const float*)d_in[1];
    const float* eps1   = (const float*)d_in[2];
    const float* eps    = (const float*)d_in[3];
    const float* fw_Wih = (const float*)d_in[4];
    const float* fw_Whh = (const float*)d_in[5];
    const float* fw_b   = (const float*)d_in[6];
    const float* bw_Wih = (const float*)d_in[7];
    const float* bw_b   = (const float*)d_in[9];
    const float* i1w = (const float*)d_in[10];
    const float* i1b = (const float*)d_in[11];
    const float* i2w = (const float*)d_in[12];
    const float* i2b = (const float*)d_in[13];
    const float* z1w = (const float*)d_in[14];
    const float* z1b = (const float*)d_in[15];
    const float* z2w = (const float*)d_in[16];
    const float* z2b = (const float*)d_in[17];
    const float* wp_w1 = (const float*)d_in[18];
    const float* wp_b1 = (const float*)d_in[19];
    const float* wp_w2 = (const float*)d_in[20];
    const float* wp_b2 = (const float*)d_in[21];
    const float* vp_w1 = (const float*)d_in[22];
    const float* vp_b1 = (const float*)d_in[23];
    const float* vp_w2 = (const float*)d_in[24];
    const float* vp_b2 = (const float*)d_in[25];
    const float* ob_w1 = (const float*)d_in[26];
    const float* ob_b1 = (const float*)d_in[27];
    const float* ob_w2 = (const float*)d_in[28];
    const float* ob_b2 = (const float*)d_in[29];
    const float* Amat  = (const float*)d_in[30];
    const float* Bmat  = (const float*)d_in[31];
    const float* Cmat  = (const float*)d_in[32];
    float* out = (float*)d_out;

    unsigned short* xgb = (unsigned short*)d_ws;                      // N*T*4H bf16
    float* h0  = (float*)(xgb + (size_t)NB*TT*G4);
    float* zb  = h0  + (size_t)NB*HHH;
    float* wm  = zb  + (size_t)NB*TT*DZZ;
    float* wsd = wm  + (size_t)NB*TT*DWW;
    float* acc = wsd + (size_t)NB*TT*DWW;
    unsigned short* blstm = (unsigned short*)(acc + 64);              // 4 tiles
    unsigned short* bob   = blstm + (size_t)4*16384;                  // 3 tiles
    unsigned short* bfragx= bob   + (size_t)3*16384;                  // 256 tiles
    unsigned short* fragP = bfragx+ (size_t)256*512;                  // 80 tiles
    unsigned char*  frag8 = (unsigned char*)(fragP + (size_t)80*512); // 8 x 64KB
    unsigned short* IPx   = (unsigned short*)(frag8 + (size_t)8*65536); // 32*127*2048 hw
    unsigned short* IPL   = IPx + (size_t)32*127*2048;
    unsigned short* IE    = IPL + (size_t)32*127*2048;                // 32*127*1024 hw
    unsigned char*  IUf   = (unsigned char*)(IE + (size_t)32*127*1024);

    hipMemsetAsync(acc, 0, 4*sizeof(float), stream);

    k_prep8b<<<64, 256, 0, stream>>>(wp_w1, wp_w2, vp_w1, vp_w2,
                                     Amat, Bmat, Cmat, frag8);
    k_prep_p<<<80, 256, 0, stream>>>(wp_w1, vp_w1, fragP);
    k_prep_xg<<<256, 256, 0, stream>>>(fw_Wih, bfragx);
    k_prep_lo<<<7, 256, 0, stream>>>(fw_Whh, ob_w1, ob_w2, blstm, bob);
    k_prep_in<<<dim3(32,127), 256, 0, stream>>>(u, eps, IE, IUf);
    k_pxu <<<dim3(32,127), 512, 0, stream>>>(x, u, wp_b1, vp_b1, fragP, IPx, IPL);
    k_xg2 <<<NB*TT/16, 512, 0, stream>>>(x, bfragx, fw_b, xgb);
    k_lstm<<<NB/2, 256, 0, stream>>>(xgb, blstm, h0);
    k_init<<<NB/4, 256, 0, stream>>>(x, bw_Wih, bw_b, i1w, i1b, i2w, i2b,
                                     z1w, z1b, z2w, z2b, eps1, h0, zb, wm, wsd);
    k_scan<<<32, 512, 0, stream>>>(wp_b2, vp_b2, frag8, IPx, IPL, IE, IUf,
                                   zb, wm, wsd);
    k_ob  <<<NB*TT/32, 256, 0, stream>>>(x, zb, ob_b1, ob_b2, bob, acc);
    k_kl  <<<NB*TT*DWW/4096, 256, 0, stream>>>(wm, wsd, acc);
    k_final<<<1, 64, 0, stream>>>(acc, out);
}

// Round 12
// 2686.247 us; speedup vs baseline: 1.1131x; 1.0616x over previous
//
#include <hip/hip_runtime.h>
#include <stdint.h>
#include <math.h>

#define NB  512
#define TT  128
#define DXX 256
#define DUU 32
#define DZZ 128
#define DWW 64
#define MMM 16
#define HHH 128
#define G4  512   // 4*H

typedef __attribute__((ext_vector_type(8))) short bf16x8;
typedef __attribute__((ext_vector_type(4))) float f32x4;
#define MFMA(a,b,c) __builtin_amdgcn_mfma_f32_16x16x32_bf16(a,b,c,0,0,0)
#define MF8(a,b,c)  __builtin_amdgcn_mfma_f32_16x16x32_fp8_fp8(a,b,c,0,0,0)

__device__ __forceinline__ float sigf(float x){ return 1.f/(1.f+__expf(-x)); }
__device__ __forceinline__ float fast_tanh(float x){
    float e = __expf(2.f*x);
    return 1.f - 2.f/(e + 1.f);
}
__device__ __forceinline__ unsigned int f2bf(float f){
    uint32_t u = __float_as_uint(f);
    uint32_t r = (u + 0x7fffu + ((u >> 16) & 1u)) >> 16;
    return r;
}
__device__ __forceinline__ float bf2f(unsigned short u){
    return __uint_as_float(((uint32_t)u) << 16);
}
// OCP e4m3fn encode, RNE, subnormal-correct, clamp to +-448
__device__ __forceinline__ unsigned int f2e4m3(float f){
    uint32_t u = __float_as_uint(f);
    uint32_t s = (u >> 24) & 0x80u;
    uint32_t a = u & 0x7fffffffu;
    if (a >= 0x43e00000u) return s | 0x7eu;
    int exp = (int)(a >> 23) - 127;
    uint32_t mant = a & 0x7fffffu;
    uint32_t code;
    if (exp >= -6){
        uint32_t keep = ((uint32_t)(exp + 7) << 3) | (mant >> 20);
        uint32_t rem = mant & 0xfffffu;
        if (rem > 0x80000u || (rem == 0x80000u && (keep & 1))) keep++;
        code = keep;
        if (code >= 0x7fu) code = 0x7eu;
    } else {
        int rs = 14 - exp;
        if (rs >= 33) return s;
        uint64_t full = (uint64_t)(mant | 0x800000u);
        uint64_t q = full >> rs;
        uint64_t rem = full & (((uint64_t)1 << rs) - 1);
        uint64_t half = (uint64_t)1 << (rs - 1);
        if (rem > half || (rem == half && (q & 1))) q++;
        code = (uint32_t)q;
    }
    return s | code;
}

__device__ __forceinline__ void stage1k(const void* gsrc, void* ldst, int ln)
{
    __builtin_amdgcn_global_load_lds(
        (const __attribute__((address_space(1))) void*)((const char*)gsrc + ln*16),
        (__attribute__((address_space(3))) void*)ldst, 16, 0, 0);
}
__device__ __forceinline__ void stage32k(const void* gsrc, void* ldst, int tid)
{
    const char* g = (const char*)gsrc;
    char* l = (char*)ldst;
    const int lane = tid & 63;
    const int wv   = tid >> 6;
    #pragma unroll
    for (int it = 0; it < 8; it++){
        const int off = it*4096 + wv*1024;
        __builtin_amdgcn_global_load_lds(
            (const __attribute__((address_space(1))) void*)(g + off + lane*16),
            (__attribute__((address_space(3))) void*)(l + off),
            16, 0, 0);
    }
}

// ===========================================================================
// k_prep8b: ALL scan weights as fp8 frags (x16 scale), per-wave LINEAR blob.
// Per wave: 128 frags x 512B = 64KB. frag f (col=wv*16+(lane&15),
// kk=(lane>>4)*8+j):
//   f<4 : G1z wp_w1[col][256+f*32+kk]
//   f<8 : G3z vp_w1[col][(f-4)*32+kk]
//   f<12: G2  wp_w2[col][(f-8)*32+kk]
//   f<16: G4  (wv0 only) vp_w2[col&15][(f-12)*32+kk]
//   else: ABC fi=f-16: m=fi/7, kt=fi%7, k=kt*32+kk over [z128|u32|w64]
// ===========================================================================
__global__ __launch_bounds__(256) void k_prep8b(
    const float* __restrict__ wp_w1, const float* __restrict__ wp_w2,
    const float* __restrict__ vp_w1, const float* __restrict__ vp_w2,
    const float* __restrict__ Amat,  const float* __restrict__ Bmat,
    const float* __restrict__ Cmat,  unsigned char* __restrict__ frag8)
{
    const int wv = blockIdx.x >> 3, c = blockIdx.x & 7;
    unsigned char* dst = frag8 + (size_t)(wv*8 + c)*8192;
    for (int d = threadIdx.x*4; d < 8192; d += 1024){
        uint32_t pk = 0;
        #pragma unroll
        for (int i = 0; i < 4; i++){
            const int B = d + i;
            const int f = 16*c + (B >> 9), r = B & 511;
            const int lane = r >> 3, jj = r & 7;
            const int col = wv*16 + (lane & 15);
            const int kk = (lane >> 4)*8 + jj;
            float v = 0.f;
            if (f < 4)       v = wp_w1[(size_t)col*416 + 256 + f*32 + kk];
            else if (f < 8)  v = vp_w1[(size_t)col*160 + (f-4)*32 + kk];
            else if (f < 12) v = wp_w2[(size_t)col*128 + (f-8)*32 + kk];
            else if (f < 16){ if (wv == 0) v = vp_w2[(size_t)(col&15)*128 + (f-12)*32 + kk]; }
            else {
                const int fi = f-16, m = fi/7, kt = fi%7;
                const int k = kt*32 + kk;
                if (k < 128)      v = Amat[((size_t)m*128 + col)*128 + k];
                else if (k < 160) v = Bmat[((size_t)m*128 + col)*32 + (k-128)];
                else              v = Cmat[((size_t)m*128 + col)*64 + (k-160)];
            }
            pk |= f2e4m3(v * 16.f) << (8*i);
        }
        *(uint32_t*)(dst + d) = pk;
    }
}

// ===========================================================================
// k_prep_p: bf16 A-frags for k_pxu (unchanged)
// ===========================================================================
__global__ __launch_bounds__(256) void k_prep_p(
    const float* __restrict__ wp_w1, const float* __restrict__ vp_w1,
    unsigned short* __restrict__ fragP)
{
    const int ct = blockIdx.x / 10, f = blockIdx.x % 10;
    unsigned short* dst = fragP + (size_t)blockIdx.x*512;
    for (int e = threadIdx.x; e < 512; e += 256){
        const int lane = e >> 3, j = e & 7;
        const int col = 16*ct + (lane & 15);
        const int kk = (lane >> 4)*8 + j;
        float v;
        if (f < 8)      v = wp_w1[(size_t)col*416 + f*32 + kk];
        else if (f == 8) v = wp_w1[(size_t)col*416 + 384 + kk];
        else             v = vp_w1[(size_t)col*160 + 128 + kk];
        dst[e] = (unsigned short)f2bf(v);
    }
}

// ---------------------------------------------------------------------------
// k_prep_xg / k_prep_lo (unchanged)
// ---------------------------------------------------------------------------
__global__ __launch_bounds__(256) void k_prep_xg(const float* __restrict__ Wih,
                                                 unsigned short* __restrict__ fragx)
{
    const int T = blockIdx.x;
    const int ct = T >> 3, kt = T & 7;
    unsigned short* dst = fragx + (size_t)T*512;
    for (int e = threadIdx.x; e < 512; e += 256){
        const int lane = e >> 3, j = e & 7;
        const int m16 = lane & 15, kq = lane >> 4;
        const int kk = 8*kq + j;
        float v = Wih[(size_t)(16*ct + m16)*DXX + 32*kt + kk];
        dst[e] = (unsigned short)f2bf(v);
    }
}

__global__ __launch_bounds__(256) void k_prep_lo(
    const float* __restrict__ Whh,
    const float* __restrict__ ob_w1, const float* __restrict__ ob_w2,
    unsigned short* __restrict__ blstm, unsigned short* __restrict__ bob)
{
    const int tile = blockIdx.x;
    unsigned short* dst; int lt;
    if (tile < 4){ dst = blstm + (size_t)tile*16384; lt = 1; }
    else { dst = bob + (size_t)(tile-4)*16384; lt = 2; }
    for (int e = threadIdx.x; e < 16384; e += 256){
        const int g = e >> 7, p = e & 127;
        const int s = p >> 3, j = p & 7;
        const int k = ((s ^ (g & 7)) << 3) | j;
        float v;
        if (lt == 1) v = Whh[(size_t)(tile*128 + g)*128 + k];
        else {
            const int tt = tile - 4;
            if (tt == 0) v = ob_w1[g*128 + k];
            else         v = ob_w2[(size_t)((tt-1)*128 + g)*128 + k];
        }
        dst[e] = (unsigned short)f2bf(v);
    }
}

// ===========================================================================
// k_prep_in: bf16 eps image (IE) + fp8 u image (IUf)  (unchanged)
// ===========================================================================
__global__ __launch_bounds__(256) void k_prep_in(
    const float* __restrict__ U, const float* __restrict__ EPS,
    unsigned short* __restrict__ IE, unsigned char* __restrict__ IUf)
{
    const int b  = blockIdx.x;
    const int tt = blockIdx.y;
    const int n0 = b*16;
    unsigned short* de = IE + ((size_t)b*127 + tt)*1024;
    for (int h = threadIdx.x; h < 1024; h += 256){
        const int e2 = h >> 9, l = (h >> 3) & 63, j = h & 7;
        const int r = 8*e2 + (l >> 3);
        de[h] = (unsigned short)f2bf(EPS[((size_t)(n0+r)*TT + tt+1)*DWW + (l&7)*8 + j]);
    }
    unsigned char* df = IUf + ((size_t)b*127 + tt)*512;
    for (int h = threadIdx.x; h < 512; h += 256){
        const int smp = h >> 5, sp = (h >> 3) & 3, j = h & 7;
        const int ud = ((sp ^ (smp & 3))*8) + j;
        df[h] = (unsigned char)f2e4m3(U[((size_t)(n0+smp)*TT + tt)*DUU + ud]);
    }
}

// ===========================================================================
// k_pxu: Px/PL precompute (unchanged)
// ===========================================================================
__global__ __launch_bounds__(512) void k_pxu(
    const float* __restrict__ X, const float* __restrict__ U,
    const float* __restrict__ wp_b1, const float* __restrict__ vp_b1,
    const unsigned short* __restrict__ fragP,
    unsigned short* __restrict__ IPx, unsigned short* __restrict__ IPL)
{
    __shared__ __align__(16) short sXl[16*256];
    __shared__ __align__(16) short sUl[16*32];
    const int tid = threadIdx.x;
    const int b = blockIdx.x, t = blockIdx.y;
    const int n0 = b*16;
    const int wv = tid >> 6, ln = tid & 63;
    const int rr = ln & 15, q = ln >> 4;
    const int sx7 = rr & 7;
    {
        const int r = tid >> 5, sl = tid & 31;
        const float* xp = &X[((size_t)(n0+r)*TT + t+1)*DXX + sl*8];
        float4 a0 = *(const float4*)xp;
        float4 a1 = *(const float4*)(xp+4);
        int4 pk;
        pk.x = f2bf(a0.x) | (f2bf(a0.y)<<16);
        pk.y = f2bf(a0.z) | (f2bf(a0.w)<<16);
        pk.z = f2bf(a1.x) | (f2bf(a1.y)<<16);
        pk.w = f2bf(a1.z) | (f2bf(a1.w)<<16);
        *(int4*)&sXl[r*256 + ((sl ^ (r&7))<<3)] = pk;
    }
    {
        const int r = tid >> 5, cc = tid & 31;
        sUl[r*32 + (((cc>>3) ^ (r&3))<<3) + (cc&7)] =
            (unsigned short)f2bf(U[((size_t)(n0+r)*TT + t)*DUU + cc]);
    }
    __syncthreads();
    const short* pA = (const short*)fragP + (size_t)wv*10*512 + ln*8;
    f32x4 d = {0.f,0.f,0.f,0.f};
    #pragma unroll
    for (int kt = 0; kt < 8; kt++){
        bf16x8 a = *(const bf16x8*)(pA + kt*512);
        bf16x8 bx = *(const bf16x8*)&sXl[rr*256 + (((4*kt+q) ^ sx7)<<3)];
        d = MFMA(a, bx, d);
    }
    bf16x8 bu = *(const bf16x8*)&sUl[rr*32 + ((q ^ (rr&3))<<3)];
    d = MFMA(*(const bf16x8*)(pA + 8*512), bu, d);
    f32x4 dl = {0.f,0.f,0.f,0.f};
    dl = MFMA(*(const bf16x8*)(pA + 9*512), bu, dl);
    const f32x4 b1v = *(const f32x4*)&wp_b1[wv*16 + q*4];
    const f32x4 bLv = *(const f32x4*)&vp_b1[wv*16 + q*4];
    d = d + b1v;
    dl = dl + bLv;
    const size_t base = ((size_t)b*127 + t)*2048
                      + rr*128 + (((2*wv + (q>>1)) ^ sx7)<<3) + (q&1)*4;
    uint2 p1, p2;
    p1.x = f2bf(d[0]) | (f2bf(d[1])<<16);
    p1.y = f2bf(d[2]) | (f2bf(d[3])<<16);
    p2.x = f2bf(dl[0]) | (f2bf(dl[1])<<16);
    p2.y = f2bf(dl[2]) | (f2bf(dl[3])<<16);
    *(uint2*)&IPx[base] = p1;
    *(uint2*)&IPL[base] = p2;
}

// ---------------------------------------------------------------------------
// fp32 dense helper (k_init only)
// ---------------------------------------------------------------------------
template<int ACT>
__device__ void dense(const float* __restrict__ W, const float* __restrict__ bias,
                      int C, int K, const float* sIn, int ldi,
                      float* sOut, int ldo, float* sWt)
{
    const int tid = threadIdx.x;
    const int g   = tid & 127;
    const int rq  = tid >> 7;
    const int r0  = 2*rq, r1 = 2*rq+1;
    for (int cb = 0; cb < C; cb += 128){
        float acc0 = 0.f, acc1 = 0.f;
        for (int kb = 0; kb < K; kb += 64){
            const int kw = (K - kb < 64) ? (K - kb) : 64;
            __syncthreads();
            if (kw == 64){
                for (int l = tid; l < 128*64; l += 256){
                    int gg = l >> 6, kk = l & 63;
                    int cx = cb + gg;
                    sWt[gg*65 + kk] = (cx < C) ? W[(size_t)cx*K + kb + kk] : 0.f;
                }
            } else {
                for (int l = tid; l < 128*32; l += 256){
                    int gg = l >> 5, kk = l & 31;
                    int cx = cb + gg;
                    sWt[gg*65 + kk] = (cx < C) ? W[(size_t)cx*K + kb + kk] : 0.f;
                }
            }
            __syncthreads();
            const float* ip0 = sIn + r0*ldi + kb;
            const float* ip1 = sIn + r1*ldi + kb;
            const float* wp  = sWt + g*65;
            #pragma unroll 8
            for (int k = 0; k < kw; k++){
                float wv = wp[k];
                acc0 += ip0[k]*wv;
                acc1 += ip1[k]*wv;
            }
        }
        int cx = cb + g;
        if (cx < C){
            float b = bias ? bias[cx] : 0.f;
            float v0 = acc0 + b, v1 = acc1 + b;
            if (ACT == 1){ v0 = fmaxf(v0, 0.f); v1 = fmaxf(v1, 0.f); }
            else if (ACT == 2){ v0 = fast_tanh(v0); v1 = fast_tanh(v1); }
            sOut[r0*ldo + cx] = v0;
            sOut[r1*ldo + cx] = v1;
        }
    }
}

// ---------------------------------------------------------------------------
// K1: xg GEMM (unchanged)
// ---------------------------------------------------------------------------
__global__ __launch_bounds__(512) void k_xg2(const float* __restrict__ X,
                                             const unsigned short* __restrict__ fragx,
                                             const float* __restrict__ bias,
                                             unsigned short* __restrict__ xgb)
{
    __shared__ __align__(16) short sXl[16*256];
    const int tid = threadIdx.x;
    const size_t row0 = (size_t)blockIdx.x * 16;
    const int wv = tid >> 6, ln = tid & 63;
    const int rr = ln & 15, q = ln >> 4;
    const int sx7 = rr & 7;
    {
        const int r = tid >> 5, sl = tid & 31;
        const float* xp = &X[(row0 + r)*DXX + sl*8];
        float4 a0 = *(const float4*)xp;
        float4 a1 = *(const float4*)(xp+4);
        int4 pk;
        pk.x = f2bf(a0.x) | (f2bf(a0.y)<<16);
        pk.y = f2bf(a0.z) | (f2bf(a0.w)<<16);
        pk.z = f2bf(a1.x) | (f2bf(a1.y)<<16);
        pk.w = f2bf(a1.z) | (f2bf(a1.w)<<16);
        *(int4*)&sXl[r*256 + ((sl ^ (r&7))<<3)] = pk;
    }
    __syncthreads();
    #pragma unroll
    for (int ci = 0; ci < 4; ci++){
        const int ct = wv*4 + ci;
        const short* pA = (const short*)fragx + (size_t)(ct*8)*512 + ln*8;
        bf16x8 af[8];
        #pragma unroll
        for (int kt = 0; kt < 8; kt++) af[kt] = *(const bf16x8*)(pA + kt*512);
        f32x4 d = {0.f,0.f,0.f,0.f};
        #pragma unroll
        for (int kt = 0; kt < 8; kt++){
            bf16x8 b = *(const bf16x8*)&sXl[rr*256 + (((4*kt+q) ^ sx7)<<3)];
            d = MFMA(af[kt], b, d);
        }
        const f32x4 bb = *(const f32x4*)&bias[ct*16 + q*4];
        uint2 pk;
        pk.x = f2bf(d[0]+bb[0]) | (f2bf(d[1]+bb[1])<<16);
        pk.y = f2bf(d[2]+bb[2]) | (f2bf(d[3]+bb[3])<<16);
        *(uint2*)&xgb[(row0 + rr)*G4 + ct*16 + q*4] = pk;
    }
}

// ---------------------------------------------------------------------------
// K2: forward LSTM (unchanged)
// ---------------------------------------------------------------------------
__global__ __launch_bounds__(256) void k_lstm(const unsigned short* __restrict__ xgb,
                                              const unsigned short* __restrict__ blob,
                                              float* __restrict__ h0)
{
    __shared__ __align__(16) char sWh[4][32768];
    __shared__ __align__(16) float sHh[2][128];
    const int tid = threadIdx.x;
    const int n0 = blockIdx.x * 2;
    const int g = tid & 127, rh = tid >> 7;
    #pragma unroll
    for (int i = 0; i < 4; i++)
        stage32k((const char*)blob + (size_t)i*32768, sWh[i], tid);
    sHh[tid >> 7][tid & 127] = 0.f;
    float cc = 0.f;
    asm volatile("s_waitcnt vmcnt(0)" ::: "memory");
    __syncthreads();
    const size_t xbase = ((size_t)(n0+rh)*TT)*G4 + g;
    for (int t = 0; t < TT; t++){
        float xv[4];
        #pragma unroll
        for (int ct = 0; ct < 4; ct++) xv[ct] = bf2f(xgb[xbase + (size_t)t*G4 + ct*128]);
        float a[4] = {0.f,0.f,0.f,0.f};
        #pragma unroll
        for (int s = 0; s < 16; s++){
            const float* ip = &sHh[rh][s*8];
            float4 u0 = *(const float4*)ip;
            float4 u1 = *(const float4*)(ip+4);
            float in[8] = {u0.x,u0.y,u0.z,u0.w,u1.x,u1.y,u1.z,u1.w};
            #pragma unroll
            for (int ct = 0; ct < 4; ct++){
                const uint32_t* wp = (const uint32_t*)(sWh[ct] + g*256 + ((s ^ (g & 7)) << 4));
                #pragma unroll
                for (int d = 0; d < 4; d++){
                    uint32_t w2 = wp[d];
                    a[ct] = fmaf(__uint_as_float(w2 << 16),        in[2*d],   a[ct]);
                    a[ct] = fmaf(__uint_as_float(w2 & 0xffff0000u), in[2*d+1], a[ct]);
                }
            }
        }
        __syncthreads();
        float ii = sigf(a[0] + xv[0]);
        float ff = sigf(a[1] + xv[1]);
        float gg = fast_tanh(a[2] + xv[2]);
        float oo = sigf(a[3] + xv[3]);
        cc = ff*cc + ii*gg;
        float hh = oo*fast_tanh(cc);
        sHh[rh][g] = hh;
        __syncthreads();
    }
    h0[(size_t)(n0+rh)*HHH + g] = sHh[rh][g];
}

// ---------------------------------------------------------------------------
// K3: init net (unchanged)
// ---------------------------------------------------------------------------
__global__ __launch_bounds__(256) void k_init(
    const float* __restrict__ X,
    const float* __restrict__ bw_Wih, const float* __restrict__ bw_b,
    const float* __restrict__ i1w, const float* __restrict__ i1b,
    const float* __restrict__ i2w, const float* __restrict__ i2b,
    const float* __restrict__ z1w, const float* __restrict__ z1b,
    const float* __restrict__ z2w, const float* __restrict__ z2b,
    const float* __restrict__ eps1, const float* __restrict__ h0,
    float* __restrict__ zb, float* __restrict__ wm, float* __restrict__ wsd)
{
    __shared__ float sX[4*260];
    __shared__ float sG[4*516];
    __shared__ float sH0[4*260];
    __shared__ float sT[4*132];
    __shared__ float sP[4*132];
    __shared__ float sWt[128*65];
    const int tid = threadIdx.x;
    const int n0  = blockIdx.x * 4;
    for (int l = tid; l < 4*256; l += 256){
        int r = l >> 8, k = l & 255;
        sX[r*260+k] = X[((size_t)(n0+r)*TT + (TT-1))*DXX + k];
    }
    for (int l = tid; l < 4*128; l += 256){
        int r = l >> 7, j = l & 127;
        sH0[r*260+j] = h0[(size_t)(n0+r)*HHH + j];
    }
    dense<0>(bw_Wih, bw_b, 512, 256, sX, 260, sG, 516, sWt);
    __syncthreads();
    for (int l = tid; l < 4*128; l += 256){
        int r = l >> 7, j = l & 127;
        float gi = sG[r*516 + j];
        float gv = sG[r*516 + 256 + j];
        float go = sG[r*516 + 384 + j];
        float c  = sigf(gi)*fast_tanh(gv);
        sH0[r*260 + 128 + j] = sigf(go)*fast_tanh(c);
    }
    dense<1>(i1w, i1b, 128, 256, sH0, 260, sT, 132, sWt);
    dense<0>(i2w, i2b, 128, 128, sT, 132, sP, 132, sWt);
    __syncthreads();
    for (int l = tid; l < 4*64; l += 256){
        int r = l >> 6, j = l & 63;
        float m0 = sP[r*132 + j];
        float s0 = __expf(sP[r*132 + 64 + j]) + 1e-5f;
        float w1 = m0 + s0*eps1[(size_t)(n0+r)*DWW + j];
        wm[((size_t)(n0+r)*TT)*DWW + j]  = m0;
        wsd[((size_t)(n0+r)*TT)*DWW + j] = s0;
        sX[r*68 + j] = w1;
    }
    dense<1>(z1w, z1b, 128, 64, sX, 68, sT, 132, sWt);
    dense<0>(z2w, z2b, 128, 128, sT, 132, sP, 132, sWt);
    __syncthreads();
    for (int l = tid; l < 4*128; l += 256){
        int r = l >> 7, j = l & 127;
        zb[((size_t)(n0+r)*TT)*DZZ + j] = sP[r*132+j];
    }
}

// ===========================================================================
// K4: all-fp8 MFMA scan. R12: head (16 frags, 8KB/wave) LDS-RESIDENT (loaded
// once); ABC streamed as 14 chunks x 4KB (vmcnt(4) pacing, 2-buf ring).
// Blob layout identical to R11 (head = bytes 0..8191; ABC chunk c at
// 8192 + c*4096).
// ===========================================================================
#define VWAIT4() do{ asm volatile("s_waitcnt vmcnt(4)" ::: "memory"); \
                    __builtin_amdgcn_sched_barrier(0); }while(0)
#define LWAIT() do{ asm volatile("s_waitcnt lgkmcnt(0)" ::: "memory"); \
                    __builtin_amdgcn_sched_barrier(0); }while(0)
#define BAR()   __builtin_amdgcn_s_barrier()

__global__ __launch_bounds__(512) void k_scan(
    const float* __restrict__ wp_b2, const float* __restrict__ vp_b2,
    const unsigned char* __restrict__ frag8,
    const unsigned short* __restrict__ IPx, const unsigned short* __restrict__ IPL,
    const unsigned short* __restrict__ IE, const unsigned char* __restrict__ IUf,
    float* __restrict__ zb, float* __restrict__ wm, float* __restrict__ wsd)
{
    __shared__ __align__(16) short sRing[32768];   // 8 waves x 2 bufs x 4KB
    __shared__ __align__(16) short sHead[32768];   // 8 waves x 8KB resident
    __shared__ __align__(16) short sPx[2048];      // bf16 Px image
    __shared__ __align__(16) short sPL[2048];      // bf16 PL image
    __shared__ __align__(16) char  sZf[2048];      // fp8 z
    __shared__ __align__(16) char  sUf[2][512];    // fp8 u dbuf
    __shared__ __align__(16) char  sWf[1024];      // fp8 w
    __shared__ __align__(16) short sEr[1024];      // bf16 eps
    __shared__ __align__(16) char  sH1f[2048];     // fp8 h1
    __shared__ __align__(16) char  sH2f[2048];     // fp8 h2
    __shared__ __align__(16) float sPW[16*132];
    __shared__ __align__(16) float sL [16*20];
    __shared__ float sAl[16*17];

    const int tid = threadIdx.x;
    const int n0  = blockIdx.x * 16;
    const int wv  = tid >> 6;
    const int ln  = tid & 63;
    const int smp = ln & 15, q = ln >> 4;
    const int sx7 = smp & 7;
    char* ringB = (char*)sRing + wv*8192;
    char* headB = (char*)sHead + wv*8192;
    const unsigned char* myblob = frag8 + (size_t)wv*65536;

    const f32x4 bw2 = *(const f32x4*)&wp_b2[wv*16 + q*4];
    f32x4 bv2 = {0.f,0.f,0.f,0.f};
    if (wv == 0) bv2 = *(const f32x4*)&vp_b2[q*4];

    #define ISSUE_CHUNK(cc_) do{ const int c2_ = (cc_) % 14; \
        _Pragma("unroll") \
        for (int k4 = 0; k4 < 4; k4++) \
            stage1k(myblob + 8192 + (size_t)c2_*4096 + k4*1024, \
                    ringB + (c2_&1)*4096 + k4*1024, ln); }while(0)
    #define HF8(f_)    (*(const long*)(headB + (f_)*512 + ln*8))
    #define AF8(c_,p_) (*(const long*)(ringB + ((c_)&1)*4096 + (p_)*512 + ln*8))
    #define BH1F(t_) (*(const long*)&sH1f[smp*128 + (((4*(t_)+q) ^ sx7)<<3)])
    #define BH2F(t_) (*(const long*)&sH2f[smp*128 + (((4*(t_)+q) ^ sx7)<<3)])

    auto issue_inputs = [&](int tt){
        const size_t ib = (size_t)blockIdx.x*127 + tt;
        if (wv < 4) stage1k((const char*)IPx + ib*4096 + wv*1024, (char*)sPx + wv*1024, ln);
        else        stage1k((const char*)IPL + ib*4096 + (wv-4)*1024, (char*)sPL + (wv-4)*1024, ln);
        if (wv == 0)      stage1k((const char*)IE + ib*2048,        (char*)sEr,        ln);
        else if (wv == 1) stage1k((const char*)IE + ib*2048 + 1024, (char*)sEr + 1024, ln);
        else if (wv == 2){ if (ln < 32) stage1k((const char*)IUf + ib*512, sUf[tt&1], ln); }
    };

    // ---- prologue ----
    issue_inputs(0);
    if (tid < 256){
        const int zs = tid >> 4, sl = tid & 15;
        const float* zp = &zb[((size_t)(n0+zs)*TT)*DZZ + sl*8];
        float4 a0 = *(const float4*)zp;
        float4 a1 = *(const float4*)(zp+4);
        uint2 p8;
        p8.x = f2e4m3(a0.x) | (f2e4m3(a0.y)<<8) | (f2e4m3(a0.z)<<16) | (f2e4m3(a0.w)<<24);
        p8.y = f2e4m3(a1.x) | (f2e4m3(a1.y)<<8) | (f2e4m3(a1.z)<<16) | (f2e4m3(a1.w)<<24);
        *(uint2*)&sZf[zs*128 + ((sl ^ (zs&7))<<3)] = p8;
    }
    #pragma unroll
    for (int k8 = 0; k8 < 8; k8++)
        stage1k(myblob + k8*1024, headB + k8*1024, ln);
    ISSUE_CHUNK(0);
    ISSUE_CHUNK(1);
    asm volatile("s_waitcnt vmcnt(0)" ::: "memory");
    __builtin_amdgcn_sched_barrier(0);
    LWAIT(); BAR();

    for (int t = 0; t < TT-1; t++){
        long bz0 = *(const long*)&sZf[smp*128 + (((0*4+q) ^ sx7)<<3)];
        long bz1 = *(const long*)&sZf[smp*128 + (((1*4+q) ^ sx7)<<3)];
        long bz2 = *(const long*)&sZf[smp*128 + (((2*4+q) ^ sx7)<<3)];
        long bz3 = *(const long*)&sZf[smp*128 + (((3*4+q) ^ sx7)<<3)];

        // ============ phase A: d1 = G1z.z ; d3 = G3z.z (head-resident)
        f32x4 d1a = {0.f,0.f,0.f,0.f}, d1b = {0.f,0.f,0.f,0.f};
        d1a = MF8(HF8(0), bz0, d1a); d1b = MF8(HF8(1), bz1, d1b);
        d1a = MF8(HF8(2), bz2, d1a); d1b = MF8(HF8(3), bz3, d1b);
        f32x4 d3a = {0.f,0.f,0.f,0.f}, d3b = {0.f,0.f,0.f,0.f};
        d3a = MF8(HF8(4), bz0, d3a); d3b = MF8(HF8(5), bz1, d3b);
        d3a = MF8(HF8(6), bz2, d3a); d3b = MF8(HF8(7), bz3, d3b);
        {
            const int basep = smp*128 + (((2*wv + (q>>1)) ^ sx7)<<3) + (q&1)*4;
            uint2 pxw = *(const uint2*)&sPx[basep];
            uint2 plw = *(const uint2*)&sPL[basep];
            f32x4 d1 = d1a + d1b, d3 = d3a + d3b;
            float v0 = fast_tanh(d1[0]*0.0625f + bf2f((unsigned short)(pxw.x & 0xffff)));
            float v1 = fast_tanh(d1[1]*0.0625f + bf2f((unsigned short)(pxw.x >> 16)));
            float v2 = fast_tanh(d1[2]*0.0625f + bf2f((unsigned short)(pxw.y & 0xffff)));
            float v3 = fast_tanh(d1[3]*0.0625f + bf2f((unsigned short)(pxw.y >> 16)));
            const int baseh = smp*128 + (((2*wv + (q>>1)) ^ sx7)<<3) + (q&1)*4;
            *(unsigned int*)&sH1f[baseh] =
                f2e4m3(v0) | (f2e4m3(v1)<<8) | (f2e4m3(v2)<<16) | (f2e4m3(v3)<<24);
            float w0 = fmaxf(d3[0]*0.0625f + bf2f((unsigned short)(plw.x & 0xffff)), 0.f);
            float w1 = fmaxf(d3[1]*0.0625f + bf2f((unsigned short)(plw.x >> 16)), 0.f);
            float w2 = fmaxf(d3[2]*0.0625f + bf2f((unsigned short)(plw.y & 0xffff)), 0.f);
            float w3 = fmaxf(d3[3]*0.0625f + bf2f((unsigned short)(plw.y >> 16)), 0.f);
            *(unsigned int*)&sH2f[baseh] =
                f2e4m3(w0) | (f2e4m3(w1)<<8) | (f2e4m3(w2)<<16) | (f2e4m3(w3)<<24);
        }
        LWAIT(); BAR();

        // ============ phase B: d2 = G2.h1 -> sPW ; wv0: d4 = G4.h2 -> sL
        {
            f32x4 d2a = {0.f,0.f,0.f,0.f}, d2b = {0.f,0.f,0.f,0.f};
            d2a = MF8(HF8(8),  BH1F(0), d2a); d2b = MF8(HF8(9),  BH1F(1), d2b);
            d2a = MF8(HF8(10), BH1F(2), d2a); d2b = MF8(HF8(11), BH1F(3), d2b);
            f32x4 o = (d2a + d2b)*0.0625f + bw2;
            *(f32x4*)&sPW[smp*132 + wv*16 + q*4] = o;
            if (wv == 0){
                f32x4 d4a = {0.f,0.f,0.f,0.f}, d4b = {0.f,0.f,0.f,0.f};
                d4a = MF8(HF8(12), BH2F(0), d4a); d4b = MF8(HF8(13), BH2F(1), d4b);
                d4a = MF8(HF8(14), BH2F(2), d4a); d4b = MF8(HF8(15), BH2F(3), d4b);
                f32x4 o4 = (d4a + d4b)*0.0625f + bv2;
                *(f32x4*)&sL[smp*20 + q*4] = o4;
            }
        }
        LWAIT(); BAR();

        // ============ phase C: w-update + softmax (alpha/16) + input prefetch
        {
            const int cs = wv, cj = ln;
            float e0 = bf2f((unsigned short)sEr[cs*64 + cj]);
            float e1 = bf2f((unsigned short)sEr[(cs+8)*64 + cj]);
            float m0 = sPW[cs*132 + cj];
            float s0 = __expf(sPW[cs*132 + 64 + cj]) + 0.01f;
            float m1 = sPW[(cs+8)*132 + cj];
            float s1 = __expf(sPW[(cs+8)*132 + 64 + cj]) + 0.01f;
            float w0 = m0 + s0*e0;
            float w1 = m1 + s1*e1;
            wm [((size_t)(n0+cs  )*TT + t+1)*DWW + cj] = m0;
            wsd[((size_t)(n0+cs  )*TT + t+1)*DWW + cj] = s0;
            wm [((size_t)(n0+cs+8)*TT + t+1)*DWW + cj] = m1;
            wsd[((size_t)(n0+cs+8)*TT + t+1)*DWW + cj] = s1;
            const int sw = cj >> 3;
            sWf[ cs   *64 + ((sw ^ ( cs   &7))<<3) + (cj&7)] = (char)f2e4m3(w0);
            sWf[(cs+8)*64 + ((sw ^ ((cs+8)&7))<<3) + (cj&7)] = (char)f2e4m3(w1);
        }
        if (tid < 16){
            float mx = -1e30f;
            #pragma unroll
            for (int m = 0; m < 16; m++) mx = fmaxf(mx, sL[tid*20+m]);
            float ss = 0.f;
            float ex[16];
            #pragma unroll
            for (int m = 0; m < 16; m++){ ex[m] = __expf(sL[tid*20+m]-mx); ss += ex[m]; }
            float inv = 0.0625f/ss;
            #pragma unroll
            for (int m = 0; m < 16; m++) sAl[tid*17+m] = ex[m]*inv;
        }
        if (t < TT-2) issue_inputs(t+1);
        LWAIT(); BAR();

        // ============ phase D: ABC walk, 14 chunks x 8 frags
        long bu8 = *(const long*)&sUf[t&1][smp*32 + ((q ^ (smp&3))<<3)];
        long bw80 = *(const long*)&sWf[smp*64 + ((q ^ sx7)<<3)];
        long bw81 = *(const long*)&sWf[smp*64 + (((4+q) ^ sx7)<<3)];
        f32x4 zac = {0.f,0.f,0.f,0.f};
        f32x4 da = {0.f,0.f,0.f,0.f}, db = {0.f,0.f,0.f,0.f};
        #pragma unroll
        for (int c = 0; c < 14; c++){
            VWAIT4();                              // chunk c landed
            #pragma unroll
            for (int p = 0; p < 8; p++){
                const int fi = 8*c + p;            // 0..111
                const int m  = fi/7, kt = fi%7;
                long a = AF8(c, p);
                long b;
                if (kt == 0) b = bz0;
                else if (kt == 1) b = bz1;
                else if (kt == 2) b = bz2;
                else if (kt == 3) b = bz3;
                else if (kt == 4) b = bu8;
                else if (kt == 5) b = bw80;
                else b = bw81;
                if (kt & 1) db = MF8(a, b, db);
                else        da = MF8(a, b, da);
                if (kt == 6){
                    const float al = sAl[smp*17 + m];
                    f32x4 s = da + db;
                    zac[0] += al*s[0]; zac[1] += al*s[1];
                    zac[2] += al*s[2]; zac[3] += al*s[3];
                    da = (f32x4){0.f,0.f,0.f,0.f};
                    db = (f32x4){0.f,0.f,0.f,0.f};
                }
            }
            ISSUE_CHUNK(c+2);                      // c=12 -> c0', c=13 -> c1'
        }
        LWAIT(); BAR();                            // all reads of z/u/w done

        // epilogue: z_{t+1} -> sZf (fp8), zb (f32)
        {
            const int slotz = 2*wv + (q>>1);
            unsigned int p8 = f2e4m3(zac[0]) | (f2e4m3(zac[1])<<8)
                            | (f2e4m3(zac[2])<<16) | (f2e4m3(zac[3])<<24);
            *(unsigned int*)&sZf[smp*128 + ((slotz ^ sx7)<<3) + (q&1)*4] = p8;
            float4 st = {zac[0], zac[1], zac[2], zac[3]};
            *(float4*)&zb[((size_t)(n0+smp)*TT + t+1)*DZZ + wv*16 + q*4] = st;
        }
        LWAIT(); BAR();
    }
    asm volatile("s_waitcnt vmcnt(0) lgkmcnt(0)" ::: "memory");
    #undef ISSUE_CHUNK
    #undef HF8
    #undef AF8
    #undef BH1F
    #undef BH2F
}

// ---------------------------------------------------------------------------
// K5: reconstruction + squared-error (unchanged)
// ---------------------------------------------------------------------------
__global__ __launch_bounds__(256) void k_ob(const float* __restrict__ X,
        const float* __restrict__ zb,
        const float* __restrict__ b1, const float* __restrict__ b2,
        const unsigned short* __restrict__ blob, float* __restrict__ acc)
{
    __shared__ __align__(16) char  sW[2][32768];
    __shared__ __align__(16) float sZ[32*128];
    __shared__ __align__(16) float sH[32*128];
    __shared__ float redb[4];
    const int tid = threadIdx.x;
    const size_t row0 = (size_t)blockIdx.x * 32;
    const int g = tid & 127, rh = tid >> 7;
    for (int l = tid; l < 32*128; l += 256)
        sZ[l] = zb[(row0 + (size_t)(l >> 7))*DZZ + (l & 127)];
    stage32k((const char*)blob, sW[0], tid);
    asm volatile("s_waitcnt vmcnt(0)" ::: "memory");
    __syncthreads();
    stage32k((const char*)blob + 32768, sW[1], tid);
    float h[16];
    #pragma unroll
    for (int r = 0; r < 16; r++) h[r] = 0.f;
    #pragma unroll 4
    for (int s = 0; s < 16; s++){
        const uint32_t* wp = (const uint32_t*)(sW[0] + g*256 + ((s ^ (g & 7)) << 4));
        float wv[8];
        #pragma unroll
        for (int d = 0; d < 4; d++){
            uint32_t w2 = wp[d];
            wv[2*d]   = __uint_as_float(w2 << 16);
            wv[2*d+1] = __uint_as_float(w2 & 0xffff0000u);
        }
        #pragma unroll
        for (int r = 0; r < 16; r++){
            const float* ip = &sZ[(rh*16+r)*128 + s*8];
            float4 u0 = *(const float4*)ip;
            float4 u1 = *(const float4*)(ip+4);
            h[r] = fmaf(wv[0],u0.x, fmaf(wv[1],u0.y, fmaf(wv[2],u0.z, fmaf(wv[3],u0.w, h[r]))));
            h[r] = fmaf(wv[4],u1.x, fmaf(wv[5],u1.y, fmaf(wv[6],u1.z, fmaf(wv[7],u1.w, h[r]))));
        }
    }
    {
        const float bb1 = b1[g];
        #pragma unroll
        for (int r = 0; r < 16; r++){
            h[r] = fmaxf(h[r] + bb1, 0.f);
            sH[(rh*16+r)*128 + g] = h[r];
        }
    }
    asm volatile("s_waitcnt vmcnt(0)" ::: "memory");
    __syncthreads();
    float errs = 0.f;
    stage32k((const char*)blob + 65536, sW[0], tid);
    #pragma unroll 1
    for (int cb = 0; cb < 2; cb++){
        const char* wt = cb ? (const char*)sW[0] : (const char*)sW[1];
        float a2[16];
        #pragma unroll
        for (int r = 0; r < 16; r++) a2[r] = 0.f;
        #pragma unroll 4
        for (int s = 0; s < 16; s++){
            const uint32_t* wp = (const uint32_t*)(wt + g*256 + ((s ^ (g & 7)) << 4));
            float wv[8];
            #pragma unroll
            for (int d = 0; d < 4; d++){
                uint32_t w2 = wp[d];
                wv[2*d]   = __uint_as_float(w2 << 16);
                wv[2*d+1] = __uint_as_float(w2 & 0xffff0000u);
            }
            #pragma unroll
            for (int r = 0; r < 16; r++){
                const float* ip = &sH[(rh*16+r)*128 + s*8];
                float4 u0 = *(const float4*)ip;
                float4 u1 = *(const float4*)(ip+4);
                a2[r] = fmaf(wv[0],u0.x, fmaf(wv[1],u0.y, fmaf(wv[2],u0.z, fmaf(wv[3],u0.w, a2[r]))));
                a2[r] = fmaf(wv[4],u1.x, fmaf(wv[5],u1.y, fmaf(wv[6],u1.z, fmaf(wv[7],u1.w, a2[r]))));
            }
        }
        const float bb2 = b2[cb*128 + g];
        #pragma unroll
        for (int r = 0; r < 16; r++){
            float xr = a2[r] + bb2;
            float xv = X[(row0 + rh*16 + r)*DXX + cb*128 + g];
            float e = xv - xr;
            errs += e*e;
        }
        if (cb == 0){
            asm volatile("s_waitcnt vmcnt(0)" ::: "memory");
            __syncthreads();
        }
    }
    for (int o = 32; o > 0; o >>= 1) errs += __shfl_down(errs, o);
    if ((tid & 63) == 0) redb[tid >> 6] = errs;
    __syncthreads();
    if (tid == 0) atomicAdd(acc, redb[0]+redb[1]+redb[2]+redb[3]);
}

// ---------------------------------------------------------------------------
// K6: KL partial sums (unchanged)
// ---------------------------------------------------------------------------
__global__ __launch_bounds__(256) void k_kl(const float* __restrict__ wm,
                                            const float* __restrict__ wsd,
                                            float* __restrict__ acc)
{
    __shared__ float red[3][4];
    const int tid = threadIdx.x;
    const size_t base = (size_t)blockIdx.x * 4096 + tid;
    float s2 = 0.f, s3 = 0.f, s4 = 0.f;
    #pragma unroll
    for (int it = 0; it < 16; it++){
        size_t i = base + (size_t)it*256;
        float sd = wsd[i], mv = wm[i];
        s2 += sd; s3 += mv*mv; s4 += __logf(sd);
    }
    for (int o = 32; o > 0; o >>= 1){
        s2 += __shfl_down(s2, o); s3 += __shfl_down(s3, o); s4 += __shfl_down(s4, o);
    }
    if ((tid & 63) == 0){ int w = tid >> 6; red[0][w]=s2; red[1][w]=s3; red[2][w]=s4; }
    __syncthreads();
    if (tid == 0) atomicAdd(acc+1, red[0][0]+red[0][1]+red[0][2]+red[0][3]);
    if (tid == 1) atomicAdd(acc+2, red[1][0]+red[1][1]+red[1][2]+red[1][3]);
    if (tid == 2) atomicAdd(acc+3, red[2][0]+red[2][1]+red[2][2]+red[2][3]);
}

__global__ void k_final(const float* __restrict__ acc, float* __restrict__ out)
{
    if (threadIdx.x == 0 && blockIdx.x == 0){
        const double LOG2PI = 1.8378770664093453;
        double logpx_c = 0.5 * (double)NB * TT * DXX * LOG2PI;
        double kl = 0.5 * ((double)acc[1] + (double)acc[2]
                           - (double)NB*TT*DWW - (double)acc[3]);
        out[0] = (float)(0.5*(double)acc[0] + logpx_c + kl);
    }
}

// ---------------------------------------------------------------------------
extern "C" void kernel_launch(void* const* d_in, const int* in_sizes, int n_in,
                              void* d_out, int out_size, void* d_ws, size_t ws_size,
                              hipStream_t stream)
{
    (void)in_sizes; (void)n_in; (void)out_size; (void)ws_size;
    const float* x      = (const float*)d_in[0];
    const float* u      = (const float*)d_in[1];
    const float* eps1   = (const float*)d_in[2];
    const float* eps    = (const float*)d_in[3];
    const float* fw_Wih = (const float*)d_in[4];
    const float* fw_Whh = (const float*)d_in[5];
    const float* fw_b   = (const float*)d_in[6];
    const float* bw_Wih = (const float*)d_in[7];
    const float* bw_b   = (const float*)d_in[9];
    const float* i1w = (const float*)d_in[10];
    const float* i1b = (const float*)d_in[11];
    const float* i2w = (const float*)d_in[12];
    const float* i2b = (const float*)d_in[13];
    const float* z1w = (const float*)d_in[14];
    const float* z1b = (const float*)d_in[15];
    const float* z2w = (const float*)d_in[16];
    const float* z2b = (const float*)d_in[17];
    const float* wp_w1 = (const float*)d_in[18];
    const float* wp_b1 = (const float*)d_in[19];
    const float* wp_w2 = (const float*)d_in[20];
    const float* wp_b2 = (const float*)d_in[21];
    const float* vp_w1 = (const float*)d_in[22];
    const float* vp_b1 = (const float*)d_in[23];
    const float* vp_w2 = (const float*)d_in[24];
    const float* vp_b2 = (const float*)d_in[25];
    const float* ob_w1 = (const float*)d_in[26];
    const float* ob_b1 = (const float*)d_in[27];
    const float* ob_w2 = (const float*)d_in[28];
    const float* ob_b2 = (const float*)d_in[29];
    const float* Amat  = (const float*)d_in[30];
    const float* Bmat  = (const float*)d_in[31];
    const float* Cmat  = (const float*)d_in[32];
    float* out = (float*)d_out;

    unsigned short* xgb = (unsigned short*)d_ws;                      // N*T*4H bf16
    float* h0  = (float*)(xgb + (size_t)NB*TT*G4);
    float* zb  = h0  + (size_t)NB*HHH;
    float* wm  = zb  + (size_t)NB*TT*DZZ;
    float* wsd = wm  + (size_t)NB*TT*DWW;
    float* acc = wsd + (size_t)NB*TT*DWW;
    unsigned short* blstm = (unsigned short*)(acc + 64);              // 4 tiles
    unsigned short* bob   = blstm + (size_t)4*16384;                  // 3 tiles
    unsigned short* bfragx= bob   + (size_t)3*16384;                  // 256 tiles
    unsigned short* fragP = bfragx+ (size_t)256*512;                  // 80 tiles
    unsigned char*  frag8 = (unsigned char*)(fragP + (size_t)80*512); // 8 x 64KB
    unsigned short* IPx   = (unsigned short*)(frag8 + (size_t)8*65536); // 32*127*2048 hw
    unsigned short* IPL   = IPx + (size_t)32*127*2048;
    unsigned short* IE    = IPL + (size_t)32*127*2048;                // 32*127*1024 hw
    unsigned char*  IUf   = (unsigned char*)(IE + (size_t)32*127*1024);

    hipMemsetAsync(acc, 0, 4*sizeof(float), stream);

    k_prep8b<<<64, 256, 0, stream>>>(wp_w1, wp_w2, vp_w1, vp_w2,
                                     Amat, Bmat, Cmat, frag8);
    k_prep_p<<<80, 256, 0, stream>>>(wp_w1, vp_w1, fragP);
    k_prep_xg<<<256, 256, 0, stream>>>(fw_Wih, bfragx);
    k_prep_lo<<<7, 256, 0, stream>>>(fw_Whh, ob_w1, ob_w2, blstm, bob);
    k_prep_in<<<dim3(32,127), 256, 0, stream>>>(u, eps, IE, IUf);
    k_pxu <<<dim3(32,127), 512, 0, stream>>>(x, u, wp_b1, vp_b1, fragP, IPx, IPL);
    k_xg2 <<<NB*TT/16, 512, 0, stream>>>(x, bfragx, fw_b, xgb);
    k_lstm<<<NB/2, 256, 0, stream>>>(xgb, blstm, h0);
    k_init<<<NB/4, 256, 0, stream>>>(x, bw_Wih, bw_b, i1w, i1b, i2w, i2b,
                                     z1w, z1b, z2w, z2b, eps1, h0, zb, wm, wsd);
    k_scan<<<32, 512, 0, stream>>>(wp_b2, vp_b2, frag8, IPx, IPL, IE, IUf,
                                   zb, wm, wsd);
    k_ob  <<<NB*TT/32, 256, 0, stream>>>(x, zb, ob_b1, ob_b2, bob, acc);
    k_kl  <<<NB*TT*DWW/4096, 256, 0, stream>>>(wm, wsd, acc);
    k_final<<<1, 64, 0, stream>>>(acc, out);
}

// Round 13
// 2577.596 us; speedup vs baseline: 1.1600x; 1.0422x over previous
//
#include <hip/hip_runtime.h>
#include <stdint.h>
#include <math.h>

#define NB  512
#define TT  128
#define DXX 256
#define DUU 32
#define DZZ 128
#define DWW 64
#define MMM 16
#define HHH 128
#define G4  512   // 4*H

typedef __attribute__((ext_vector_type(8))) short bf16x8;
typedef __attribute__((ext_vector_type(4))) float f32x4;
typedef __attribute__((ext_vector_type(2))) long longx2;
#define MFMA(a,b,c) __builtin_amdgcn_mfma_f32_16x16x32_bf16(a,b,c,0,0,0)
#define MF8(a,b,c)  __builtin_amdgcn_mfma_f32_16x16x32_fp8_fp8(a,b,c,0,0,0)

__device__ __forceinline__ float sigf(float x){ return 1.f/(1.f+__expf(-x)); }
__device__ __forceinline__ float fast_tanh(float x){
    float e = __expf(2.f*x);
    return 1.f - 2.f/(e + 1.f);
}
__device__ __forceinline__ unsigned int f2bf(float f){
    uint32_t u = __float_as_uint(f);
    uint32_t r = (u + 0x7fffu + ((u >> 16) & 1u)) >> 16;
    return r;
}
__device__ __forceinline__ float bf2f(unsigned short u){
    return __uint_as_float(((uint32_t)u) << 16);
}
// OCP e4m3fn encode, RNE, subnormal-correct, clamp to +-448
__device__ __forceinline__ unsigned int f2e4m3(float f){
    uint32_t u = __float_as_uint(f);
    uint32_t s = (u >> 24) & 0x80u;
    uint32_t a = u & 0x7fffffffu;
    if (a >= 0x43e00000u) return s | 0x7eu;
    int exp = (int)(a >> 23) - 127;
    uint32_t mant = a & 0x7fffffu;
    uint32_t code;
    if (exp >= -6){
        uint32_t keep = ((uint32_t)(exp + 7) << 3) | (mant >> 20);
        uint32_t rem = mant & 0xfffffu;
        if (rem > 0x80000u || (rem == 0x80000u && (keep & 1))) keep++;
        code = keep;
        if (code >= 0x7fu) code = 0x7eu;
    } else {
        int rs = 14 - exp;
        if (rs >= 33) return s;
        uint64_t full = (uint64_t)(mant | 0x800000u);
        uint64_t q = full >> rs;
        uint64_t rem = full & (((uint64_t)1 << rs) - 1);
        uint64_t half = (uint64_t)1 << (rs - 1);
        if (rem > half || (rem == half && (q & 1))) q++;
        code = (uint32_t)q;
    }
    return s | code;
}

__device__ __forceinline__ void stage1k(const void* gsrc, void* ldst, int ln)
{
    __builtin_amdgcn_global_load_lds(
        (const __attribute__((address_space(1))) void*)((const char*)gsrc + ln*16),
        (__attribute__((address_space(3))) void*)ldst, 16, 0, 0);
}
__device__ __forceinline__ void stage32k(const void* gsrc, void* ldst, int tid)
{
    const char* g = (const char*)gsrc;
    char* l = (char*)ldst;
    const int lane = tid & 63;
    const int wv   = tid >> 6;
    #pragma unroll
    for (int it = 0; it < 8; it++){
        const int off = it*4096 + wv*1024;
        __builtin_amdgcn_global_load_lds(
            (const __attribute__((address_space(1))) void*)(g + off + lane*16),
            (__attribute__((address_space(3))) void*)(l + off),
            16, 0, 0);
    }
}

// ===========================================================================
// k_prep8b: fp8 weights (x16 scale), per-wave 64KB blob:
//   bytes [0,8192): HEAD, old frag layout (frag f at f*512 + lane*8):
//     f<4: G1z wp_w1[col][256+f*32+kk]; f<8: G3z vp_w1[col][(f-4)*32+kk];
//     f<12: G2 wp_w2[col][(f-8)*32+kk]; f<16: G4 (wv0) vp_w2[col&15][..]
//   bytes [8192,65536): ABC, 14 chunks x 4KB LANE-MAJOR:
//     byte = 8192 + c*4096 + lane*64 + f8*8 + b holds weight for
//     fi=8c+f8 (m=fi/7,kt=fi%7), col=wv*16+(lane&15), k=kt*32+(lane>>4)*8+b
// blockIdx = wv*8 + cc; cc=0 -> head; cc>=1 -> chunks 2(cc-1), 2(cc-1)+1.
// ===========================================================================
__global__ __launch_bounds__(256) void k_prep8b(
    const float* __restrict__ wp_w1, const float* __restrict__ wp_w2,
    const float* __restrict__ vp_w1, const float* __restrict__ vp_w2,
    const float* __restrict__ Amat,  const float* __restrict__ Bmat,
    const float* __restrict__ Cmat,  unsigned char* __restrict__ frag8)
{
    const int wv = blockIdx.x >> 3, cc = blockIdx.x & 7;
    unsigned char* dst = frag8 + (size_t)wv*65536 + (size_t)cc*8192;
    for (int d = threadIdx.x*4; d < 8192; d += 1024){
        uint32_t pk = 0;
        #pragma unroll
        for (int i = 0; i < 4; i++){
            const int B = d + i;
            float v = 0.f;
            if (cc == 0){
                const int f = B >> 9, r = B & 511;
                const int lane = r >> 3, jj = r & 7;
                const int col = wv*16 + (lane & 15);
                const int kk = (lane >> 4)*8 + jj;
                if (f < 4)       v = wp_w1[(size_t)col*416 + 256 + f*32 + kk];
                else if (f < 8)  v = vp_w1[(size_t)col*160 + (f-4)*32 + kk];
                else if (f < 12) v = wp_w2[(size_t)col*128 + (f-8)*32 + kk];
                else { if (wv == 0) v = vp_w2[(size_t)(col&15)*128 + (f-12)*32 + kk]; }
            } else {
                const int c = 2*(cc-1) + (B >> 12);
                const int r = B & 4095;
                const int lane = r >> 6, f8 = (r >> 3) & 7, b = r & 7;
                const int fi = 8*c + f8;          // 0..111
                const int m = fi/7, kt = fi%7;
                const int col = wv*16 + (lane & 15);
                const int k = kt*32 + (lane >> 4)*8 + b;
                if (k < 128)      v = Amat[((size_t)m*128 + col)*128 + k];
                else if (k < 160) v = Bmat[((size_t)m*128 + col)*32 + (k-128)];
                else              v = Cmat[((size_t)m*128 + col)*64 + (k-160)];
            }
            pk |= f2e4m3(v * 16.f) << (8*i);
        }
        *(uint32_t*)(dst + d) = pk;
    }
}

// ===========================================================================
// k_prep_p: bf16 A-frags for k_pxu (unchanged)
// ===========================================================================
__global__ __launch_bounds__(256) void k_prep_p(
    const float* __restrict__ wp_w1, const float* __restrict__ vp_w1,
    unsigned short* __restrict__ fragP)
{
    const int ct = blockIdx.x / 10, f = blockIdx.x % 10;
    unsigned short* dst = fragP + (size_t)blockIdx.x*512;
    for (int e = threadIdx.x; e < 512; e += 256){
        const int lane = e >> 3, j = e & 7;
        const int col = 16*ct + (lane & 15);
        const int kk = (lane >> 4)*8 + j;
        float v;
        if (f < 8)      v = wp_w1[(size_t)col*416 + f*32 + kk];
        else if (f == 8) v = wp_w1[(size_t)col*416 + 384 + kk];
        else             v = vp_w1[(size_t)col*160 + 128 + kk];
        dst[e] = (unsigned short)f2bf(v);
    }
}

// ---------------------------------------------------------------------------
// k_prep_xg / k_prep_lo (unchanged)
// ---------------------------------------------------------------------------
__global__ __launch_bounds__(256) void k_prep_xg(const float* __restrict__ Wih,
                                                 unsigned short* __restrict__ fragx)
{
    const int T = blockIdx.x;
    const int ct = T >> 3, kt = T & 7;
    unsigned short* dst = fragx + (size_t)T*512;
    for (int e = threadIdx.x; e < 512; e += 256){
        const int lane = e >> 3, j = e & 7;
        const int m16 = lane & 15, kq = lane >> 4;
        const int kk = 8*kq + j;
        float v = Wih[(size_t)(16*ct + m16)*DXX + 32*kt + kk];
        dst[e] = (unsigned short)f2bf(v);
    }
}

__global__ __launch_bounds__(256) void k_prep_lo(
    const float* __restrict__ Whh,
    const float* __restrict__ ob_w1, const float* __restrict__ ob_w2,
    unsigned short* __restrict__ blstm, unsigned short* __restrict__ bob)
{
    const int tile = blockIdx.x;
    unsigned short* dst; int lt;
    if (tile < 4){ dst = blstm + (size_t)tile*16384; lt = 1; }
    else { dst = bob + (size_t)(tile-4)*16384; lt = 2; }
    for (int e = threadIdx.x; e < 16384; e += 256){
        const int g = e >> 7, p = e & 127;
        const int s = p >> 3, j = p & 7;
        const int k = ((s ^ (g & 7)) << 3) | j;
        float v;
        if (lt == 1) v = Whh[(size_t)(tile*128 + g)*128 + k];
        else {
            const int tt = tile - 4;
            if (tt == 0) v = ob_w1[g*128 + k];
            else         v = ob_w2[(size_t)((tt-1)*128 + g)*128 + k];
        }
        dst[e] = (unsigned short)f2bf(v);
    }
}

// ===========================================================================
// k_prep_in: bf16 eps image (IE) + fp8 u image (IUf)  (unchanged)
// ===========================================================================
__global__ __launch_bounds__(256) void k_prep_in(
    const float* __restrict__ U, const float* __restrict__ EPS,
    unsigned short* __restrict__ IE, unsigned char* __restrict__ IUf)
{
    const int b  = blockIdx.x;
    const int tt = blockIdx.y;
    const int n0 = b*16;
    unsigned short* de = IE + ((size_t)b*127 + tt)*1024;
    for (int h = threadIdx.x; h < 1024; h += 256){
        const int e2 = h >> 9, l = (h >> 3) & 63, j = h & 7;
        const int r = 8*e2 + (l >> 3);
        de[h] = (unsigned short)f2bf(EPS[((size_t)(n0+r)*TT + tt+1)*DWW + (l&7)*8 + j]);
    }
    unsigned char* df = IUf + ((size_t)b*127 + tt)*512;
    for (int h = threadIdx.x; h < 512; h += 256){
        const int smp = h >> 5, sp = (h >> 3) & 3, j = h & 7;
        const int ud = ((sp ^ (smp & 3))*8) + j;
        df[h] = (unsigned char)f2e4m3(U[((size_t)(n0+smp)*TT + tt)*DUU + ud]);
    }
}

// ===========================================================================
// k_pxu: Px/PL precompute (unchanged)
// ===========================================================================
__global__ __launch_bounds__(512) void k_pxu(
    const float* __restrict__ X, const float* __restrict__ U,
    const float* __restrict__ wp_b1, const float* __restrict__ vp_b1,
    const unsigned short* __restrict__ fragP,
    unsigned short* __restrict__ IPx, unsigned short* __restrict__ IPL)
{
    __shared__ __align__(16) short sXl[16*256];
    __shared__ __align__(16) short sUl[16*32];
    const int tid = threadIdx.x;
    const int b = blockIdx.x, t = blockIdx.y;
    const int n0 = b*16;
    const int wv = tid >> 6, ln = tid & 63;
    const int rr = ln & 15, q = ln >> 4;
    const int sx7 = rr & 7;
    {
        const int r = tid >> 5, sl = tid & 31;
        const float* xp = &X[((size_t)(n0+r)*TT + t+1)*DXX + sl*8];
        float4 a0 = *(const float4*)xp;
        float4 a1 = *(const float4*)(xp+4);
        int4 pk;
        pk.x = f2bf(a0.x) | (f2bf(a0.y)<<16);
        pk.y = f2bf(a0.z) | (f2bf(a0.w)<<16);
        pk.z = f2bf(a1.x) | (f2bf(a1.y)<<16);
        pk.w = f2bf(a1.z) | (f2bf(a1.w)<<16);
        *(int4*)&sXl[r*256 + ((sl ^ (r&7))<<3)] = pk;
    }
    {
        const int r = tid >> 5, cc = tid & 31;
        sUl[r*32 + (((cc>>3) ^ (r&3))<<3) + (cc&7)] =
            (unsigned short)f2bf(U[((size_t)(n0+r)*TT + t)*DUU + cc]);
    }
    __syncthreads();
    const short* pA = (const short*)fragP + (size_t)wv*10*512 + ln*8;
    f32x4 d = {0.f,0.f,0.f,0.f};
    #pragma unroll
    for (int kt = 0; kt < 8; kt++){
        bf16x8 a = *(const bf16x8*)(pA + kt*512);
        bf16x8 bx = *(const bf16x8*)&sXl[rr*256 + (((4*kt+q) ^ sx7)<<3)];
        d = MFMA(a, bx, d);
    }
    bf16x8 bu = *(const bf16x8*)&sUl[rr*32 + ((q ^ (rr&3))<<3)];
    d = MFMA(*(const bf16x8*)(pA + 8*512), bu, d);
    f32x4 dl = {0.f,0.f,0.f,0.f};
    dl = MFMA(*(const bf16x8*)(pA + 9*512), bu, dl);
    const f32x4 b1v = *(const f32x4*)&wp_b1[wv*16 + q*4];
    const f32x4 bLv = *(const f32x4*)&vp_b1[wv*16 + q*4];
    d = d + b1v;
    dl = dl + bLv;
    const size_t base = ((size_t)b*127 + t)*2048
                      + rr*128 + (((2*wv + (q>>1)) ^ sx7)<<3) + (q&1)*4;
    uint2 p1, p2;
    p1.x = f2bf(d[0]) | (f2bf(d[1])<<16);
    p1.y = f2bf(d[2]) | (f2bf(d[3])<<16);
    p2.x = f2bf(dl[0]) | (f2bf(dl[1])<<16);
    p2.y = f2bf(dl[2]) | (f2bf(dl[3])<<16);
    *(uint2*)&IPx[base] = p1;
    *(uint2*)&IPL[base] = p2;
}

// ---------------------------------------------------------------------------
// fp32 dense helper (k_init only)
// ---------------------------------------------------------------------------
template<int ACT>
__device__ void dense(const float* __restrict__ W, const float* __restrict__ bias,
                      int C, int K, const float* sIn, int ldi,
                      float* sOut, int ldo, float* sWt)
{
    const int tid = threadIdx.x;
    const int g   = tid & 127;
    const int rq  = tid >> 7;
    const int r0  = 2*rq, r1 = 2*rq+1;
    for (int cb = 0; cb < C; cb += 128){
        float acc0 = 0.f, acc1 = 0.f;
        for (int kb = 0; kb < K; kb += 64){
            const int kw = (K - kb < 64) ? (K - kb) : 64;
            __syncthreads();
            if (kw == 64){
                for (int l = tid; l < 128*64; l += 256){
                    int gg = l >> 6, kk = l & 63;
                    int cx = cb + gg;
                    sWt[gg*65 + kk] = (cx < C) ? W[(size_t)cx*K + kb + kk] : 0.f;
                }
            } else {
                for (int l = tid; l < 128*32; l += 256){
                    int gg = l >> 5, kk = l & 31;
                    int cx = cb + gg;
                    sWt[gg*65 + kk] = (cx < C) ? W[(size_t)cx*K + kb + kk] : 0.f;
                }
            }
            __syncthreads();
            const float* ip0 = sIn + r0*ldi + kb;
            const float* ip1 = sIn + r1*ldi + kb;
            const float* wp  = sWt + g*65;
            #pragma unroll 8
            for (int k = 0; k < kw; k++){
                float wv = wp[k];
                acc0 += ip0[k]*wv;
                acc1 += ip1[k]*wv;
            }
        }
        int cx = cb + g;
        if (cx < C){
            float b = bias ? bias[cx] : 0.f;
            float v0 = acc0 + b, v1 = acc1 + b;
            if (ACT == 1){ v0 = fmaxf(v0, 0.f); v1 = fmaxf(v1, 0.f); }
            else if (ACT == 2){ v0 = fast_tanh(v0); v1 = fast_tanh(v1); }
            sOut[r0*ldo + cx] = v0;
            sOut[r1*ldo + cx] = v1;
        }
    }
}

// ---------------------------------------------------------------------------
// K1: xg GEMM (unchanged)
// ---------------------------------------------------------------------------
__global__ __launch_bounds__(512) void k_xg2(const float* __restrict__ X,
                                             const unsigned short* __restrict__ fragx,
                                             const float* __restrict__ bias,
                                             unsigned short* __restrict__ xgb)
{
    __shared__ __align__(16) short sXl[16*256];
    const int tid = threadIdx.x;
    const size_t row0 = (size_t)blockIdx.x * 16;
    const int wv = tid >> 6, ln = tid & 63;
    const int rr = ln & 15, q = ln >> 4;
    const int sx7 = rr & 7;
    {
        const int r = tid >> 5, sl = tid & 31;
        const float* xp = &X[(row0 + r)*DXX + sl*8];
        float4 a0 = *(const float4*)xp;
        float4 a1 = *(const float4*)(xp+4);
        int4 pk;
        pk.x = f2bf(a0.x) | (f2bf(a0.y)<<16);
        pk.y = f2bf(a0.z) | (f2bf(a0.w)<<16);
        pk.z = f2bf(a1.x) | (f2bf(a1.y)<<16);
        pk.w = f2bf(a1.z) | (f2bf(a1.w)<<16);
        *(int4*)&sXl[r*256 + ((sl ^ (r&7))<<3)] = pk;
    }
    __syncthreads();
    #pragma unroll
    for (int ci = 0; ci < 4; ci++){
        const int ct = wv*4 + ci;
        const short* pA = (const short*)fragx + (size_t)(ct*8)*512 + ln*8;
        bf16x8 af[8];
        #pragma unroll
        for (int kt = 0; kt < 8; kt++) af[kt] = *(const bf16x8*)(pA + kt*512);
        f32x4 d = {0.f,0.f,0.f,0.f};
        #pragma unroll
        for (int kt = 0; kt < 8; kt++){
            bf16x8 b = *(const bf16x8*)&sXl[rr*256 + (((4*kt+q) ^ sx7)<<3)];
            d = MFMA(af[kt], b, d);
        }
        const f32x4 bb = *(const f32x4*)&bias[ct*16 + q*4];
        uint2 pk;
        pk.x = f2bf(d[0]+bb[0]) | (f2bf(d[1]+bb[1])<<16);
        pk.y = f2bf(d[2]+bb[2]) | (f2bf(d[3]+bb[3])<<16);
        *(uint2*)&xgb[(row0 + rr)*G4 + ct*16 + q*4] = pk;
    }
}

// ---------------------------------------------------------------------------
// K2: forward LSTM (unchanged)
// ---------------------------------------------------------------------------
__global__ __launch_bounds__(256) void k_lstm(const unsigned short* __restrict__ xgb,
                                              const unsigned short* __restrict__ blob,
                                              float* __restrict__ h0)
{
    __shared__ __align__(16) char sWh[4][32768];
    __shared__ __align__(16) float sHh[2][128];
    const int tid = threadIdx.x;
    const int n0 = blockIdx.x * 2;
    const int g = tid & 127, rh = tid >> 7;
    #pragma unroll
    for (int i = 0; i < 4; i++)
        stage32k((const char*)blob + (size_t)i*32768, sWh[i], tid);
    sHh[tid >> 7][tid & 127] = 0.f;
    float cc = 0.f;
    asm volatile("s_waitcnt vmcnt(0)" ::: "memory");
    __syncthreads();
    const size_t xbase = ((size_t)(n0+rh)*TT)*G4 + g;
    for (int t = 0; t < TT; t++){
        float xv[4];
        #pragma unroll
        for (int ct = 0; ct < 4; ct++) xv[ct] = bf2f(xgb[xbase + (size_t)t*G4 + ct*128]);
        float a[4] = {0.f,0.f,0.f,0.f};
        #pragma unroll
        for (int s = 0; s < 16; s++){
            const float* ip = &sHh[rh][s*8];
            float4 u0 = *(const float4*)ip;
            float4 u1 = *(const float4*)(ip+4);
            float in[8] = {u0.x,u0.y,u0.z,u0.w,u1.x,u1.y,u1.z,u1.w};
            #pragma unroll
            for (int ct = 0; ct < 4; ct++){
                const uint32_t* wp = (const uint32_t*)(sWh[ct] + g*256 + ((s ^ (g & 7)) << 4));
                #pragma unroll
                for (int d = 0; d < 4; d++){
                    uint32_t w2 = wp[d];
                    a[ct] = fmaf(__uint_as_float(w2 << 16),        in[2*d],   a[ct]);
                    a[ct] = fmaf(__uint_as_float(w2 & 0xffff0000u), in[2*d+1], a[ct]);
                }
            }
        }
        __syncthreads();
        float ii = sigf(a[0] + xv[0]);
        float ff = sigf(a[1] + xv[1]);
        float gg = fast_tanh(a[2] + xv[2]);
        float oo = sigf(a[3] + xv[3]);
        cc = ff*cc + ii*gg;
        float hh = oo*fast_tanh(cc);
        sHh[rh][g] = hh;
        __syncthreads();
    }
    h0[(size_t)(n0+rh)*HHH + g] = sHh[rh][g];
}

// ---------------------------------------------------------------------------
// K3: init net (unchanged)
// ---------------------------------------------------------------------------
__global__ __launch_bounds__(256) void k_init(
    const float* __restrict__ X,
    const float* __restrict__ bw_Wih, const float* __restrict__ bw_b,
    const float* __restrict__ i1w, const float* __restrict__ i1b,
    const float* __restrict__ i2w, const float* __restrict__ i2b,
    const float* __restrict__ z1w, const float* __restrict__ z1b,
    const float* __restrict__ z2w, const float* __restrict__ z2b,
    const float* __restrict__ eps1, const float* __restrict__ h0,
    float* __restrict__ zb, float* __restrict__ wm, float* __restrict__ wsd)
{
    __shared__ float sX[4*260];
    __shared__ float sG[4*516];
    __shared__ float sH0[4*260];
    __shared__ float sT[4*132];
    __shared__ float sP[4*132];
    __shared__ float sWt[128*65];
    const int tid = threadIdx.x;
    const int n0  = blockIdx.x * 4;
    for (int l = tid; l < 4*256; l += 256){
        int r = l >> 8, k = l & 255;
        sX[r*260+k] = X[((size_t)(n0+r)*TT + (TT-1))*DXX + k];
    }
    for (int l = tid; l < 4*128; l += 256){
        int r = l >> 7, j = l & 127;
        sH0[r*260+j] = h0[(size_t)(n0+r)*HHH + j];
    }
    dense<0>(bw_Wih, bw_b, 512, 256, sX, 260, sG, 516, sWt);
    __syncthreads();
    for (int l = tid; l < 4*128; l += 256){
        int r = l >> 7, j = l & 127;
        float gi = sG[r*516 + j];
        float gv = sG[r*516 + 256 + j];
        float go = sG[r*516 + 384 + j];
        float c  = sigf(gi)*fast_tanh(gv);
        sH0[r*260 + 128 + j] = sigf(go)*fast_tanh(c);
    }
    dense<1>(i1w, i1b, 128, 256, sH0, 260, sT, 132, sWt);
    dense<0>(i2w, i2b, 128, 128, sT, 132, sP, 132, sWt);
    __syncthreads();
    for (int l = tid; l < 4*64; l += 256){
        int r = l >> 6, j = l & 63;
        float m0 = sP[r*132 + j];
        float s0 = __expf(sP[r*132 + 64 + j]) + 1e-5f;
        float w1 = m0 + s0*eps1[(size_t)(n0+r)*DWW + j];
        wm[((size_t)(n0+r)*TT)*DWW + j]  = m0;
        wsd[((size_t)(n0+r)*TT)*DWW + j] = s0;
        sX[r*68 + j] = w1;
    }
    dense<1>(z1w, z1b, 128, 64, sX, 68, sT, 132, sWt);
    dense<0>(z2w, z2b, 128, 128, sT, 132, sP, 132, sWt);
    __syncthreads();
    for (int l = tid; l < 4*128; l += 256){
        int r = l >> 7, j = l & 127;
        zb[((size_t)(n0+r)*TT)*DZZ + j] = sP[r*132+j];
    }
}

// ===========================================================================
// K4: all-fp8 MFMA scan. R13: ABC streamed via REGISTER double-buffer
// (direct vector loads, lane-major blob, vmcnt(4) pacing). Head LDS-resident.
// ===========================================================================
#define VWAITR() do{ asm volatile("s_waitcnt vmcnt(4)" ::: "memory"); \
                    __builtin_amdgcn_sched_barrier(0); }while(0)
#define LWAIT() do{ asm volatile("s_waitcnt lgkmcnt(0)" ::: "memory"); \
                    __builtin_amdgcn_sched_barrier(0); }while(0)
#define BAR()   __builtin_amdgcn_s_barrier()

__global__ __launch_bounds__(512) void k_scan(
    const float* __restrict__ wp_b2, const float* __restrict__ vp_b2,
    const unsigned char* __restrict__ frag8,
    const unsigned short* __restrict__ IPx, const unsigned short* __restrict__ IPL,
    const unsigned short* __restrict__ IE, const unsigned char* __restrict__ IUf,
    float* __restrict__ zb, float* __restrict__ wm, float* __restrict__ wsd)
{
    __shared__ __align__(16) short sHead[32768];   // 8 waves x 8KB resident
    __shared__ __align__(16) short sPx[2048];      // bf16 Px image
    __shared__ __align__(16) short sPL[2048];      // bf16 PL image
    __shared__ __align__(16) char  sZf[2048];      // fp8 z
    __shared__ __align__(16) char  sUf[2][512];    // fp8 u dbuf
    __shared__ __align__(16) char  sWf[1024];      // fp8 w
    __shared__ __align__(16) short sEr[1024];      // bf16 eps
    __shared__ __align__(16) char  sH1f[2048];     // fp8 h1
    __shared__ __align__(16) char  sH2f[2048];     // fp8 h2
    __shared__ __align__(16) float sPW[16*132];
    __shared__ __align__(16) float sL [16*20];
    __shared__ float sAl[16*17];

    const int tid = threadIdx.x;
    const int n0  = blockIdx.x * 16;
    const int wv  = tid >> 6;
    const int ln  = tid & 63;
    const int smp = ln & 15, q = ln >> 4;
    const int sx7 = smp & 7;
    char* headB = (char*)sHead + wv*8192;
    const unsigned char* myblob = frag8 + (size_t)wv*65536;
    const char* abase = (const char*)myblob + 8192 + ln*64;

    const f32x4 bw2 = *(const f32x4*)&wp_b2[wv*16 + q*4];
    f32x4 bv2 = {0.f,0.f,0.f,0.f};
    if (wv == 0) bv2 = *(const f32x4*)&vp_b2[q*4];

    #define LOADC(r0_,r1_,r2_,r3_,c_) do{ const char* gp_ = abase + (size_t)(c_)*4096; \
        r0_ = *(const longx2*)(gp_);      r1_ = *(const longx2*)(gp_+16); \
        r2_ = *(const longx2*)(gp_+32);   r3_ = *(const longx2*)(gp_+48); }while(0)
    #define HF8(f_)    (*(const long*)(headB + (f_)*512 + ln*8))
    #define BH1F(t_) (*(const long*)&sH1f[smp*128 + (((4*(t_)+q) ^ sx7)<<3)])
    #define BH2F(t_) (*(const long*)&sH2f[smp*128 + (((4*(t_)+q) ^ sx7)<<3)])

    auto issue_inputs = [&](int tt){
        const size_t ib = (size_t)blockIdx.x*127 + tt;
        if (wv < 4) stage1k((const char*)IPx + ib*4096 + wv*1024, (char*)sPx + wv*1024, ln);
        else        stage1k((const char*)IPL + ib*4096 + (wv-4)*1024, (char*)sPL + (wv-4)*1024, ln);
        if (wv == 0)      stage1k((const char*)IE + ib*2048,        (char*)sEr,        ln);
        else if (wv == 1) stage1k((const char*)IE + ib*2048 + 1024, (char*)sEr + 1024, ln);
        else if (wv == 2){ if (ln < 32) stage1k((const char*)IUf + ib*512, sUf[tt&1], ln); }
    };

    // ---- prologue ----
    issue_inputs(0);
    if (tid < 256){
        const int zs = tid >> 4, sl = tid & 15;
        const float* zp = &zb[((size_t)(n0+zs)*TT)*DZZ + sl*8];
        float4 a0 = *(const float4*)zp;
        float4 a1 = *(const float4*)(zp+4);
        uint2 p8;
        p8.x = f2e4m3(a0.x) | (f2e4m3(a0.y)<<8) | (f2e4m3(a0.z)<<16) | (f2e4m3(a0.w)<<24);
        p8.y = f2e4m3(a1.x) | (f2e4m3(a1.y)<<8) | (f2e4m3(a1.z)<<16) | (f2e4m3(a1.w)<<24);
        *(uint2*)&sZf[zs*128 + ((sl ^ (zs&7))<<3)] = p8;
    }
    #pragma unroll
    for (int k8 = 0; k8 < 8; k8++)
        stage1k(myblob + k8*1024, headB + k8*1024, ln);
    asm volatile("s_waitcnt vmcnt(0)" ::: "memory");
    __builtin_amdgcn_sched_barrier(0);
    LWAIT(); BAR();

    // register ABC double-buffer: chunk0 -> rA, chunk1 -> rB
    longx2 rA0, rA1, rA2, rA3, rB0, rB1, rB2, rB3;
    LOADC(rA0,rA1,rA2,rA3, 0);
    LOADC(rB0,rB1,rB2,rB3, 1);

    for (int t = 0; t < TT-1; t++){
        long bz0 = *(const long*)&sZf[smp*128 + (((0*4+q) ^ sx7)<<3)];
        long bz1 = *(const long*)&sZf[smp*128 + (((1*4+q) ^ sx7)<<3)];
        long bz2 = *(const long*)&sZf[smp*128 + (((2*4+q) ^ sx7)<<3)];
        long bz3 = *(const long*)&sZf[smp*128 + (((3*4+q) ^ sx7)<<3)];

        // ============ phase A: d1 = G1z.z ; d3 = G3z.z (head-resident)
        f32x4 d1a = {0.f,0.f,0.f,0.f}, d1b = {0.f,0.f,0.f,0.f};
        d1a = MF8(HF8(0), bz0, d1a); d1b = MF8(HF8(1), bz1, d1b);
        d1a = MF8(HF8(2), bz2, d1a); d1b = MF8(HF8(3), bz3, d1b);
        f32x4 d3a = {0.f,0.f,0.f,0.f}, d3b = {0.f,0.f,0.f,0.f};
        d3a = MF8(HF8(4), bz0, d3a); d3b = MF8(HF8(5), bz1, d3b);
        d3a = MF8(HF8(6), bz2, d3a); d3b = MF8(HF8(7), bz3, d3b);
        {
            const int basep = smp*128 + (((2*wv + (q>>1)) ^ sx7)<<3) + (q&1)*4;
            uint2 pxw = *(const uint2*)&sPx[basep];
            uint2 plw = *(const uint2*)&sPL[basep];
            f32x4 d1 = d1a + d1b, d3 = d3a + d3b;
            float v0 = fast_tanh(d1[0]*0.0625f + bf2f((unsigned short)(pxw.x & 0xffff)));
            float v1 = fast_tanh(d1[1]*0.0625f + bf2f((unsigned short)(pxw.x >> 16)));
            float v2 = fast_tanh(d1[2]*0.0625f + bf2f((unsigned short)(pxw.y & 0xffff)));
            float v3 = fast_tanh(d1[3]*0.0625f + bf2f((unsigned short)(pxw.y >> 16)));
            *(unsigned int*)&sH1f[basep] =
                f2e4m3(v0) | (f2e4m3(v1)<<8) | (f2e4m3(v2)<<16) | (f2e4m3(v3)<<24);
            float w0 = fmaxf(d3[0]*0.0625f + bf2f((unsigned short)(plw.x & 0xffff)), 0.f);
            float w1 = fmaxf(d3[1]*0.0625f + bf2f((unsigned short)(plw.x >> 16)), 0.f);
            float w2 = fmaxf(d3[2]*0.0625f + bf2f((unsigned short)(plw.y & 0xffff)), 0.f);
            float w3 = fmaxf(d3[3]*0.0625f + bf2f((unsigned short)(plw.y >> 16)), 0.f);
            *(unsigned int*)&sH2f[basep] =
                f2e4m3(w0) | (f2e4m3(w1)<<8) | (f2e4m3(w2)<<16) | (f2e4m3(w3)<<24);
        }
        LWAIT(); BAR();

        // ============ phase B: d2 = G2.h1 -> sPW ; wv0: d4 = G4.h2 -> sL
        {
            f32x4 d2a = {0.f,0.f,0.f,0.f}, d2b = {0.f,0.f,0.f,0.f};
            d2a = MF8(HF8(8),  BH1F(0), d2a); d2b = MF8(HF8(9),  BH1F(1), d2b);
            d2a = MF8(HF8(10), BH1F(2), d2a); d2b = MF8(HF8(11), BH1F(3), d2b);
            f32x4 o = (d2a + d2b)*0.0625f + bw2;
            *(f32x4*)&sPW[smp*132 + wv*16 + q*4] = o;
            if (wv == 0){
                f32x4 d4a = {0.f,0.f,0.f,0.f}, d4b = {0.f,0.f,0.f,0.f};
                d4a = MF8(HF8(12), BH2F(0), d4a); d4b = MF8(HF8(13), BH2F(1), d4b);
                d4a = MF8(HF8(14), BH2F(2), d4a); d4b = MF8(HF8(15), BH2F(3), d4b);
                f32x4 o4 = (d4a + d4b)*0.0625f + bv2;
                *(f32x4*)&sL[smp*20 + q*4] = o4;
            }
        }
        LWAIT(); BAR();

        // ============ phase C: w-update + softmax (alpha/16) + input prefetch
        {
            const int cs = wv, cj = ln;
            float e0 = bf2f((unsigned short)sEr[cs*64 + cj]);
            float e1 = bf2f((unsigned short)sEr[(cs+8)*64 + cj]);
            float m0 = sPW[cs*132 + cj];
            float s0 = __expf(sPW[cs*132 + 64 + cj]) + 0.01f;
            float m1 = sPW[(cs+8)*132 + cj];
            float s1 = __expf(sPW[(cs+8)*132 + 64 + cj]) + 0.01f;
            float w0 = m0 + s0*e0;
            float w1 = m1 + s1*e1;
            wm [((size_t)(n0+cs  )*TT + t+1)*DWW + cj] = m0;
            wsd[((size_t)(n0+cs  )*TT + t+1)*DWW + cj] = s0;
            wm [((size_t)(n0+cs+8)*TT + t+1)*DWW + cj] = m1;
            wsd[((size_t)(n0+cs+8)*TT + t+1)*DWW + cj] = s1;
            const int sw = cj >> 3;
            sWf[ cs   *64 + ((sw ^ ( cs   &7))<<3) + (cj&7)] = (char)f2e4m3(w0);
            sWf[(cs+8)*64 + ((sw ^ ((cs+8)&7))<<3) + (cj&7)] = (char)f2e4m3(w1);
        }
        if (tid < 16){
            float mx = -1e30f;
            #pragma unroll
            for (int m = 0; m < 16; m++) mx = fmaxf(mx, sL[tid*20+m]);
            float ss = 0.f;
            float ex[16];
            #pragma unroll
            for (int m = 0; m < 16; m++){ ex[m] = __expf(sL[tid*20+m]-mx); ss += ex[m]; }
            float inv = 0.0625f/ss;
            #pragma unroll
            for (int m = 0; m < 16; m++) sAl[tid*17+m] = ex[m]*inv;
        }
        if (t < TT-2) issue_inputs(t+1);
        LWAIT(); BAR();

        // ============ phase D: ABC walk, 14 chunks x 8 frags, reg dbuf
        long bu8 = *(const long*)&sUf[t&1][smp*32 + ((q ^ (smp&3))<<3)];
        long bw80 = *(const long*)&sWf[smp*64 + ((q ^ sx7)<<3)];
        long bw81 = *(const long*)&sWf[smp*64 + (((4+q) ^ sx7)<<3)];
        f32x4 zac = {0.f,0.f,0.f,0.f};
        f32x4 da = {0.f,0.f,0.f,0.f}, db = {0.f,0.f,0.f,0.f};
        #define CHUNK_MFMA(R0_,R1_,R2_,R3_,c_) do{ \
            _Pragma("unroll") \
            for (int p = 0; p < 8; p++){ \
                const int fi = 8*(c_) + p; \
                const int m_ = fi/7, kt_ = fi%7; \
                long a_ = (p<2) ? R0_[p&1] : (p<4) ? R1_[p&1] : (p<6) ? R2_[p&1] : R3_[p&1]; \
                long b_; \
                if (kt_ == 0) b_ = bz0; else if (kt_ == 1) b_ = bz1; \
                else if (kt_ == 2) b_ = bz2; else if (kt_ == 3) b_ = bz3; \
                else if (kt_ == 4) b_ = bu8; else if (kt_ == 5) b_ = bw80; \
                else b_ = bw81; \
                if (kt_ & 1) db = MF8(a_, b_, db); else da = MF8(a_, b_, da); \
                if (kt_ == 6){ \
                    const float al_ = sAl[smp*17 + m_]; \
                    f32x4 s_ = da + db; \
                    zac[0] += al_*s_[0]; zac[1] += al_*s_[1]; \
                    zac[2] += al_*s_[2]; zac[3] += al_*s_[3]; \
                    da = (f32x4){0.f,0.f,0.f,0.f}; \
                    db = (f32x4){0.f,0.f,0.f,0.f}; \
                } \
            } }while(0)
        #pragma unroll
        for (int cp = 0; cp < 7; cp++){
            VWAITR();                              // chunk 2cp landed (newest 4 = 2cp+1)
            CHUNK_MFMA(rA0,rA1,rA2,rA3, 2*cp);
            LOADC(rA0,rA1,rA2,rA3, (2*cp+2) % 14); // c=12 -> next-step chunk0
            VWAITR();                              // chunk 2cp+1 landed
            CHUNK_MFMA(rB0,rB1,rB2,rB3, 2*cp+1);
            LOADC(rB0,rB1,rB2,rB3, (2*cp+3) % 14); // c=13 -> next-step chunk1
        }
        #undef CHUNK_MFMA
        LWAIT(); BAR();                            // all reads of z/u/w done

        // epilogue: z_{t+1} -> sZf (fp8), zb (f32)
        {
            const int slotz = 2*wv + (q>>1);
            unsigned int p8 = f2e4m3(zac[0]) | (f2e4m3(zac[1])<<8)
                            | (f2e4m3(zac[2])<<16) | (f2e4m3(zac[3])<<24);
            *(unsigned int*)&sZf[smp*128 + ((slotz ^ sx7)<<3) + (q&1)*4] = p8;
            float4 st = {zac[0], zac[1], zac[2], zac[3]};
            *(float4*)&zb[((size_t)(n0+smp)*TT + t+1)*DZZ + wv*16 + q*4] = st;
        }
        LWAIT(); BAR();
    }
    asm volatile("s_waitcnt vmcnt(0) lgkmcnt(0)" ::: "memory");
    #undef LOADC
    #undef HF8
    #undef BH1F
    #undef BH2F
}

// ---------------------------------------------------------------------------
// K5: reconstruction + squared-error (unchanged)
// ---------------------------------------------------------------------------
__global__ __launch_bounds__(256) void k_ob(const float* __restrict__ X,
        const float* __restrict__ zb,
        const float* __restrict__ b1, const float* __restrict__ b2,
        const unsigned short* __restrict__ blob, float* __restrict__ acc)
{
    __shared__ __align__(16) char  sW[2][32768];
    __shared__ __align__(16) float sZ[32*128];
    __shared__ __align__(16) float sH[32*128];
    __shared__ float redb[4];
    const int tid = threadIdx.x;
    const size_t row0 = (size_t)blockIdx.x * 32;
    const int g = tid & 127, rh = tid >> 7;
    for (int l = tid; l < 32*128; l += 256)
        sZ[l] = zb[(row0 + (size_t)(l >> 7))*DZZ + (l & 127)];
    stage32k((const char*)blob, sW[0], tid);
    asm volatile("s_waitcnt vmcnt(0)" ::: "memory");
    __syncthreads();
    stage32k((const char*)blob + 32768, sW[1], tid);
    float h[16];
    #pragma unroll
    for (int r = 0; r < 16; r++) h[r] = 0.f;
    #pragma unroll 4
    for (int s = 0; s < 16; s++){
        const uint32_t* wp = (const uint32_t*)(sW[0] + g*256 + ((s ^ (g & 7)) << 4));
        float wv[8];
        #pragma unroll
        for (int d = 0; d < 4; d++){
            uint32_t w2 = wp[d];
            wv[2*d]   = __uint_as_float(w2 << 16);
            wv[2*d+1] = __uint_as_float(w2 & 0xffff0000u);
        }
        #pragma unroll
        for (int r = 0; r < 16; r++){
            const float* ip = &sZ[(rh*16+r)*128 + s*8];
            float4 u0 = *(const float4*)ip;
            float4 u1 = *(const float4*)(ip+4);
            h[r] = fmaf(wv[0],u0.x, fmaf(wv[1],u0.y, fmaf(wv[2],u0.z, fmaf(wv[3],u0.w, h[r]))));
            h[r] = fmaf(wv[4],u1.x, fmaf(wv[5],u1.y, fmaf(wv[6],u1.z, fmaf(wv[7],u1.w, h[r]))));
        }
    }
    {
        const float bb1 = b1[g];
        #pragma unroll
        for (int r = 0; r < 16; r++){
            h[r] = fmaxf(h[r] + bb1, 0.f);
            sH[(rh*16+r)*128 + g] = h[r];
        }
    }
    asm volatile("s_waitcnt vmcnt(0)" ::: "memory");
    __syncthreads();
    float errs = 0.f;
    stage32k((const char*)blob + 65536, sW[0], tid);
    #pragma unroll 1
    for (int cb = 0; cb < 2; cb++){
        const char* wt = cb ? (const char*)sW[0] : (const char*)sW[1];
        float a2[16];
        #pragma unroll
        for (int r = 0; r < 16; r++) a2[r] = 0.f;
        #pragma unroll 4
        for (int s = 0; s < 16; s++){
            const uint32_t* wp = (const uint32_t*)(wt + g*256 + ((s ^ (g & 7)) << 4));
            float wv[8];
            #pragma unroll
            for (int d = 0; d < 4; d++){
                uint32_t w2 = wp[d];
                wv[2*d]   = __uint_as_float(w2 << 16);
                wv[2*d+1] = __uint_as_float(w2 & 0xffff0000u);
            }
            #pragma unroll
            for (int r = 0; r < 16; r++){
                const float* ip = &sH[(rh*16+r)*128 + s*8];
                float4 u0 = *(const float4*)ip;
                float4 u1 = *(const float4*)(ip+4);
                a2[r] = fmaf(wv[0],u0.x, fmaf(wv[1],u0.y, fmaf(wv[2],u0.z, fmaf(wv[3],u0.w, a2[r]))));
                a2[r] = fmaf(wv[4],u1.x, fmaf(wv[5],u1.y, fmaf(wv[6],u1.z, fmaf(wv[7],u1.w, a2[r]))));
            }
        }
        const float bb2 = b2[cb*128 + g];
        #pragma unroll
        for (int r = 0; r < 16; r++){
            float xr = a2[r] + bb2;
            float xv = X[(row0 + rh*16 + r)*DXX + cb*128 + g];
            float e = xv - xr;
            errs += e*e;
        }
        if (cb == 0){
            asm volatile("s_waitcnt vmcnt(0)" ::: "memory");
            __syncthreads();
        }
    }
    for (int o = 32; o > 0; o >>= 1) errs += __shfl_down(errs, o);
    if ((tid & 63) == 0) redb[tid >> 6] = errs;
    __syncthreads();
    if (tid == 0) atomicAdd(acc, redb[0]+redb[1]+redb[2]+redb[3]);
}

// ---------------------------------------------------------------------------
// K6: KL partial sums (unchanged)
// ---------------------------------------------------------------------------
__global__ __launch_bounds__(256) void k_kl(const float* __restrict__ wm,
                                            const float* __restrict__ wsd,
                                            float* __restrict__ acc)
{
    __shared__ float red[3][4];
    const int tid = threadIdx.x;
    const size_t base = (size_t)blockIdx.x * 4096 + tid;
    float s2 = 0.f, s3 = 0.f, s4 = 0.f;
    #pragma unroll
    for (int it = 0; it < 16; it++){
        size_t i = base + (size_t)it*256;
        float sd = wsd[i], mv = wm[i];
        s2 += sd; s3 += mv*mv; s4 += __logf(sd);
    }
    for (int o = 32; o > 0; o >>= 1){
        s2 += __shfl_down(s2, o); s3 += __shfl_down(s3, o); s4 += __shfl_down(s4, o);
    }
    if ((tid & 63) == 0){ int w = tid >> 6; red[0][w]=s2; red[1][w]=s3; red[2][w]=s4; }
    __syncthreads();
    if (tid == 0) atomicAdd(acc+1, red[0][0]+red[0][1]+red[0][2]+red[0][3]);
    if (tid == 1) atomicAdd(acc+2, red[1][0]+red[1][1]+red[1][2]+red[1][3]);
    if (tid == 2) atomicAdd(acc+3, red[2][0]+red[2][1]+red[2][2]+red[2][3]);
}

__global__ void k_final(const float* __restrict__ acc, float* __restrict__ out)
{
    if (threadIdx.x == 0 && blockIdx.x == 0){
        const double LOG2PI = 1.8378770664093453;
        double logpx_c = 0.5 * (double)NB * TT * DXX * LOG2PI;
        double kl = 0.5 * ((double)acc[1] + (double)acc[2]
                           - (double)NB*TT*DWW - (double)acc[3]);
        out[0] = (float)(0.5*(double)acc[0] + logpx_c + kl);
    }
}

// ---------------------------------------------------------------------------
extern "C" void kernel_launch(void* const* d_in, const int* in_sizes, int n_in,
                              void* d_out, int out_size, void* d_ws, size_t ws_size,
                              hipStream_t stream)
{
    (void)in_sizes; (void)n_in; (void)out_size; (void)ws_size;
    const float* x      = (const float*)d_in[0];
    const float* u      = (const float*)d_in[1];
    const float* eps1   = (const float*)d_in[2];
    const float* eps    = (const float*)d_in[3];
    const float* fw_Wih = (const float*)d_in[4];
    const float* fw_Whh = (const float*)d_in[5];
    const float* fw_b   = (const float*)d_in[6];
    const float* bw_Wih = (const float*)d_in[7];
    const float* bw_b   = (const float*)d_in[9];
    const float* i1w = (const float*)d_in[10];
    const float* i1b = (const float*)d_in[11];
    const float* i2w = (const float*)d_in[12];
    const float* i2b = (const float*)d_in[13];
    const float* z1w = (const float*)d_in[14];
    const float* z1b = (const float*)d_in[15];
    const float* z2w = (const float*)d_in[16];
    const float* z2b = (const float*)d_in[17];
    const float* wp_w1 = (const float*)d_in[18];
    const float* wp_b1 = (const float*)d_in[19];
    const float* wp_w2 = (const float*)d_in[20];
    const float* wp_b2 = (const float*)d_in[21];
    const float* vp_w1 = (const float*)d_in[22];
    const float* vp_b1 = (const float*)d_in[23];
    const float* vp_w2 = (const float*)d_in[24];
    const float* vp_b2 = (const float*)d_in[25];
    const float* ob_w1 = (const float*)d_in[26];
    const float* ob_b1 = (const float*)d_in[27];
    const float* ob_w2 = (const float*)d_in[28];
    const float* ob_b2 = (const float*)d_in[29];
    const float* Amat  = (const float*)d_in[30];
    const float* Bmat  = (const float*)d_in[31];
    const float* Cmat  = (const float*)d_in[32];
    float* out = (float*)d_out;

    unsigned short* xgb = (unsigned short*)d_ws;                      // N*T*4H bf16
    float* h0  = (float*)(xgb + (size_t)NB*TT*G4);
    float* zb  = h0  + (size_t)NB*HHH;
    float* wm  = zb  + (size_t)NB*TT*DZZ;
    float* wsd = wm  + (size_t)NB*TT*DWW;
    float* acc = wsd + (size_t)NB*TT*DWW;
    unsigned short* blstm = (unsigned short*)(acc + 64);              // 4 tiles
    unsigned short* bob   = blstm + (size_t)4*16384;                  // 3 tiles
    unsigned short* bfragx= bob   + (size_t)3*16384;                  // 256 tiles
    unsigned short* fragP = bfragx+ (size_t)256*512;                  // 80 tiles
    unsigned char*  frag8 = (unsigned char*)(fragP + (size_t)80*512); // 8 x 64KB
    unsigned short* IPx   = (unsigned short*)(frag8 + (size_t)8*65536); // 32*127*2048 hw
    unsigned short* IPL   = IPx + (size_t)32*127*2048;
    unsigned short* IE    = IPL + (size_t)32*127*2048;                // 32*127*1024 hw
    unsigned char*  IUf   = (unsigned char*)(IE + (size_t)32*127*1024);

    hipMemsetAsync(acc, 0, 4*sizeof(float), stream);

    k_prep8b<<<64, 256, 0, stream>>>(wp_w1, wp_w2, vp_w1, vp_w2,
                                     Amat, Bmat, Cmat, frag8);
    k_prep_p<<<80, 256, 0, stream>>>(wp_w1, vp_w1, fragP);
    k_prep_xg<<<256, 256, 0, stream>>>(fw_Wih, bfragx);
    k_prep_lo<<<7, 256, 0, stream>>>(fw_Whh, ob_w1, ob_w2, blstm, bob);
    k_prep_in<<<dim3(32,127), 256, 0, stream>>>(u, eps, IE, IUf);
    k_pxu <<<dim3(32,127), 512, 0, stream>>>(x, u, wp_b1, vp_b1, fragP, IPx, IPL);
    k_xg2 <<<NB*TT/16, 512, 0, stream>>>(x, bfragx, fw_b, xgb);
    k_lstm<<<NB/2, 256, 0, stream>>>(xgb, blstm, h0);
    k_init<<<NB/4, 256, 0, stream>>>(x, bw_Wih, bw_b, i1w, i1b, i2w, i2b,
                                     z1w, z1b, z2w, z2b, eps1, h0, zb, wm, wsd);
    k_scan<<<32, 512, 0, stream>>>(wp_b2, vp_b2, frag8, IPx, IPL, IE, IUf,
                                   zb, wm, wsd);
    k_ob  <<<NB*TT/32, 256, 0, stream>>>(x, zb, ob_b1, ob_b2, bob, acc);
    k_kl  <<<NB*TT*DWW/4096, 256, 0, stream>>>(wm, wsd, acc);
    k_final<<<1, 64, 0, stream>>>(acc, out);
}